// Round 5
// baseline (339.658 us; speedup 1.0000x reference)
//
#include <hip/hip_runtime.h>
#include <hip/hip_bf16.h>
#include <cstdint>
#include <cstddef>

#define B_  64
#define T_  256
#define C_  2048
#define HS_ 128
#define N_  384

typedef __bf16 bf16x8 __attribute__((ext_vector_type(8)));
typedef float  floatx4 __attribute__((ext_vector_type(4)));

__device__ __forceinline__ unsigned short f2bf_rne(float f) {
  union { float f; unsigned int u; } v; v.f = f;
  unsigned int r = v.u + 0x7fffu + ((v.u >> 16) & 1u);
  return (unsigned short)(r >> 16);
}
__device__ __forceinline__ unsigned short f2bf(float f) {
  union { float f; unsigned int u; } v; v.f = f;
  return (unsigned short)((v.u + 0x8000u) >> 16);
}

// ---------------- Weight transpose + bf16 cast: Wt[w*128+h][c] = W_w[c][h] ---
__global__ __launch_bounds__(256) void wt_kernel(
    const float* __restrict__ Wk, const float* __restrict__ Wq,
    const float* __restrict__ Wv, unsigned short* __restrict__ Wt) {
  __shared__ float tile[32][33];
  const int w  = blockIdx.z;
  const int c0 = blockIdx.x * 32;
  const int h0 = blockIdx.y * 32;
  const float* W = (w == 0) ? Wk : (w == 1) ? Wq : Wv;
  const int tx = threadIdx.x & 31, ty = threadIdx.x >> 5;
#pragma unroll
  for (int i = 0; i < 32; i += 8)
    tile[ty + i][tx] = W[(size_t)(c0 + ty + i) * HS_ + h0 + tx];
  __syncthreads();
#pragma unroll
  for (int i = 0; i < 32; i += 8) {
    int hh = ty + i, cc = tx;
    Wt[(size_t)(w * HS_ + h0 + hh) * C_ + c0 + cc] = f2bf_rne(tile[cc][hh]);
  }
}

// ---------------- QKV GEMM: BM=64 x BN=192, BK=64, reg-staged, 2-deep -------
// Supply model (rounds 0-4, Little's law fits all five structures):
// per-CU vmem supply <= ~15 B/cy, achieved = in_flight_bytes/latency.
// Levers: (a) total bytes 805 -> 670 MB (BN=192: A fp32 read 2x, B all-L2);
// (b) in-flight depth: NO global_load_lds, both operands global->reg
// (2 iterations deep) -> LDS; barrier is raw "lgkmcnt(0); s_barrier" with NO
// vmcnt drain, so ~160 KB/CU of loads stay in flight across barriers.
// Both LDS tiles chunk-xor swizzled (write side is per-lane now, so swizzle
// is free). LDS = exactly 64 KB -> 2 blocks/CU. k-loop unrolled x2 with
// named register sets (no runtime-indexed register arrays).
__global__ __launch_bounds__(256, 2) void qkv_gemm(
    const float* __restrict__ X, const unsigned short* __restrict__ Wt,
    unsigned short* __restrict__ kqv, unsigned short* __restrict__ vT) {
  __shared__ unsigned short As[2][64 * 64];   // 16 KB, chunk-xor swizzled
  __shared__ unsigned short Bs[2][192 * 64];  // 48 KB, chunk-xor swizzled

  const int tid  = threadIdx.x;
  const int wave = tid >> 6, lane = tid & 63;
  const int quad = lane >> 4, l16 = lane & 15;

  const int bid = blockIdx.x;
  const int m0  = (bid & 255) * 64;    // bid and bid+256 share m-panel & XCD
  const int n0  = (bid >> 8) * 192;
  const int wm  = (wave >> 1) * 32;    // {0,32}
  const int wn  = (wave & 1) * 96;     // {0,96}

  // A map: 64 rows x 16 float4-chunks = 1024 slots = 4/thread (coalesced).
  int arow[4], achk[4], aoff[4];
#pragma unroll
  for (int r = 0; r < 4; ++r) {
    int s = r * 256 + tid;
    arow[r] = s >> 4; achk[r] = s & 15;
    // LDS short index: row*64 + ((g>>1)^(row&7))*8 + (g&1)*4
    aoff[r] = arow[r] * 64 + (((achk[r] >> 1) ^ (arow[r] & 7)) << 3) + ((achk[r] & 1) << 2);
  }
  // B map: 192 rows x 8 chunks(16B) = 1536 slots = 6/thread (coalesced).
  int bn[6], bc[6], boff[6];
#pragma unroll
  for (int r = 0; r < 6; ++r) {
    int s = r * 256 + tid;
    bn[r] = s >> 3; bc[r] = s & 7;
    boff[r] = bn[r] * 64 + ((bc[r] ^ (bn[r] & 7)) << 3);
  }

#define LOAD_A(AV, KN)                                                         \
  {                                                                            \
    _Pragma("unroll")                                                          \
    for (int r = 0; r < 4; ++r)                                                \
      AV[r] = *(const float4*)(X + (size_t)(m0 + arow[r]) * C_ + (KN) + achk[r] * 4); \
  }
#define LOAD_B(BV, KN)                                                         \
  {                                                                            \
    _Pragma("unroll")                                                          \
    for (int r = 0; r < 6; ++r)                                                \
      BV[r] = *(const uint4*)(Wt + (size_t)(n0 + bn[r]) * C_ + (KN) + bc[r] * 8); \
  }
#define STAGE(AV, BV, BUF)                                                     \
  {                                                                            \
    _Pragma("unroll")                                                          \
    for (int r = 0; r < 4; ++r) {                                              \
      ushort4 b4;                                                              \
      b4.x = f2bf(AV[r].x); b4.y = f2bf(AV[r].y);                              \
      b4.z = f2bf(AV[r].z); b4.w = f2bf(AV[r].w);                              \
      *(ushort4*)&As[BUF][aoff[r]] = b4;                                       \
    }                                                                          \
    _Pragma("unroll")                                                          \
    for (int r = 0; r < 6; ++r)                                                \
      *(uint4*)&Bs[BUF][boff[r]] = BV[r];                                      \
  }
#define BARRIER() asm volatile("s_waitcnt lgkmcnt(0)\n\ts_barrier" ::: "memory")
#define COMPUTE(BUF)                                                           \
  {                                                                            \
    _Pragma("unroll")                                                          \
    for (int ks = 0; ks < 2; ++ks) {                                           \
      bf16x8 af[2], bfv[6];                                                    \
      _Pragma("unroll")                                                        \
      for (int mt = 0; mt < 2; ++mt) {                                         \
        int row = wm + mt * 16 + l16;                                          \
        int c = ks * 4 + quad;                                                 \
        af[mt] = *(const bf16x8*)&As[BUF][row * 64 + ((c ^ (row & 7)) << 3)];  \
      }                                                                        \
      _Pragma("unroll")                                                        \
      for (int nt = 0; nt < 6; ++nt) {                                         \
        int n = wn + nt * 16 + l16;                                            \
        int c = ks * 4 + quad;                                                 \
        bfv[nt] = *(const bf16x8*)&Bs[BUF][n * 64 + ((c ^ (n & 7)) << 3)];     \
      }                                                                        \
      _Pragma("unroll")                                                        \
      for (int mt = 0; mt < 2; ++mt)                                           \
        _Pragma("unroll")                                                      \
        for (int nt = 0; nt < 6; ++nt)                                         \
          acc[mt][nt] = __builtin_amdgcn_mfma_f32_16x16x32_bf16(               \
              af[mt], bfv[nt], acc[mt][nt], 0, 0, 0);                          \
    }                                                                          \
  }

  // ---- prologue: 2-deep register prefetch (a0/b0 for k=0, a1/b1 for k=1)
  float4 a0[4], a1[4]; uint4 b0[6], b1[6];
  LOAD_A(a0, 0); LOAD_B(b0, 0);
  LOAD_A(a1, 64); LOAD_B(b1, 64);

  floatx4 acc[2][6] = {};

  // 32 K-steps, unrolled x2 (even uses a0/b0 -> buf0, odd a1/b1 -> buf1).
  // Safety: buffer BUF written at step k is read at step k (after barrier k);
  // its next overwrite (step k+2) is ordered after all waves' step-k reads by
  // barrier k+1. Loads issued at step k refill the just-consumed registers
  // for step k+2 and stay in flight across the (non-draining) barriers.
  for (int k2 = 0; k2 < 16; ++k2) {
    const int k = k2 * 2;
    // ---- even step k
    STAGE(a0, b0, 0);
    BARRIER();
    if (k2 < 15) { LOAD_A(a0, (k + 2) * 64); LOAD_B(b0, (k + 2) * 64); }
    COMPUTE(0);
    // ---- odd step k+1
    STAGE(a1, b1, 1);
    BARRIER();
    if (k2 < 15) { LOAD_A(a1, (k + 3) * 64); LOAD_B(b1, (k + 3) * 64); }
    COMPUTE(1);
  }
#undef LOAD_A
#undef LOAD_B
#undef STAGE
#undef BARRIER
#undef COMPUTE

  // ---- epilogue: C/D layout col=lane&15, row=quad*4+reg
#pragma unroll
  for (int mt = 0; mt < 2; ++mt)
#pragma unroll
    for (int nt = 0; nt < 6; ++nt)
#pragma unroll
      for (int r = 0; r < 4; ++r) {
        int row = m0 + wm + mt * 16 + quad * 4 + r;
        int col = n0 + wn + nt * 16 + l16;
        unsigned short us = f2bf(acc[mt][nt][r]);
        kqv[(size_t)row * N_ + col] = us;
        if (col >= 256) {   // V region -> also store transposed
          int bb = row >> 8, tt = row & 255;
          vT[(size_t)bb * HS_ * T_ + (size_t)(col - 256) * T_ + tt] = us;
        }
      }
}

// ---------------- Attention: 4 waves/block, 2 waves per 16-row t-tile -------
// Wave (tile, par): handles s-tiles st with st&1==par, packed densely in its
// private P buffer. Partial O (unnormalized) + partial rowsum combined in LDS.
// Tile pairing {x, 15-x}: every block carries an equal 17 units of causal
// work, so every CU gets the same load. (Part of the best 241.8 us config.)
__global__ __launch_bounds__(256) void attn_kernel(
    const unsigned short* __restrict__ kqv, const unsigned short* __restrict__ vT,
    float* __restrict__ out) {
  __shared__ unsigned short P[4][16 * 136];  // 17.4 KB, per-wave packed P
  __shared__ float Olds[2][16][132];         // 16.9 KB (pad 132)
  __shared__ float rs1[2][16];

  const int tid  = threadIdx.x;
  const int wave = tid >> 6, lane = tid & 63;
  const int quad = lane >> 4, l16 = lane & 15;
  const int tile = wave >> 1, par = wave & 1;
  const int tt = tile ? (15 - (int)blockIdx.x) : (int)blockIdx.x;  // balanced pair
  const int b  = blockIdx.y;
  const int t0 = tt * 16;
  const float scale = 0.022097086912079612f; // 2048^-0.5
  const unsigned short* kq = kqv + (size_t)b * T_ * N_;

  // k fragments (A operand), rows t0..t0+15
  bf16x8 kf[4];
#pragma unroll
  for (int ks = 0; ks < 4; ++ks)
    kf[ks] = *(const bf16x8*)&kq[(size_t)(t0 + l16) * N_ + ks * 32 + quad * 8];

  const int n_my = ((tt + 1) + (1 - par)) >> 1;  // my s-tile count
  const int npad = (n_my + 1) & ~1;              // padded to even

  float rsum[4] = {0.f, 0.f, 0.f, 0.f};

  // ---- S = k q^T over my s-tiles, exp+mask, pack into P (manual prefetch)
  bf16x8 qf[4];
  if (n_my > 0) {
    const int st = par;
#pragma unroll
    for (int ks = 0; ks < 4; ++ks)
      qf[ks] = *(const bf16x8*)&kq[(size_t)(st * 16 + l16) * N_ + HS_ + ks * 32 + quad * 8];
  }
  for (int j = 0; j < n_my; ++j) {
    bf16x8 qn[4];
    if (j + 1 < n_my) {
      const int st = par + 2 * (j + 1);
#pragma unroll
      for (int ks = 0; ks < 4; ++ks)
        qn[ks] = *(const bf16x8*)&kq[(size_t)(st * 16 + l16) * N_ + HS_ + ks * 32 + quad * 8];
    }
    floatx4 a = {};
#pragma unroll
    for (int ks = 0; ks < 4; ++ks)
      a = __builtin_amdgcn_mfma_f32_16x16x32_bf16(kf[ks], qf[ks], a, 0, 0, 0);
    const int st = par + 2 * j;
    const int scol = st * 16 + l16;
#pragma unroll
    for (int r = 0; r < 4; ++r) {
      int trow = t0 + quad * 4 + r;
      float p = (scol <= trow) ? __expf(a[r] * scale) : 0.f;
      rsum[r] += p;
      P[wave][(quad * 4 + r) * 136 + j * 16 + l16] = f2bf(p);
    }
#pragma unroll
    for (int ks = 0; ks < 4; ++ks) qf[ks] = qn[ks];
  }
  if (npad > n_my) {  // zero-fill the odd tail tile
#pragma unroll
    for (int r = 0; r < 4; ++r)
      P[wave][(quad * 4 + r) * 136 + n_my * 16 + l16] = 0;
  }
  // row sums: reduce across the 16 lanes of each quad
#pragma unroll
  for (int m = 1; m < 16; m <<= 1)
#pragma unroll
    for (int r = 0; r < 4; ++r)
      rsum[r] += __shfl_xor(rsum[r], m, 64);

  // ---- O_partial = P @ V over packed k-steps (manual prefetch)
  floatx4 oacc[8] = {};
  const unsigned short* vb = vT + (size_t)b * HS_ * T_;
  const int nks = npad >> 1;
  const int sb_off = (quad >> 1);        // which packed 16-tile inside 32-k
  const int sb_lo  = (quad & 1) * 8;
  bf16x8 bv[8]; bf16x8 pa;
  if (nks > 0) {
    int st = par + 2 * (0 + sb_off);
    int sbase = st * 16 + sb_lo;
    pa = *(const bf16x8*)&P[wave][l16 * 136 + 0 * 32 + quad * 8];
#pragma unroll
    for (int nt = 0; nt < 8; ++nt)
      bv[nt] = *(const bf16x8*)&vb[(size_t)(nt * 16 + l16) * T_ + sbase];
  }
  for (int ks2 = 0; ks2 < nks; ++ks2) {
    bf16x8 bvn[8]; bf16x8 pan;
    if (ks2 + 1 < nks) {
      int jt = 2 * (ks2 + 1) + sb_off;
      int st = par + 2 * jt;
      int sbase = st * 16 + sb_lo;
      pan = *(const bf16x8*)&P[wave][l16 * 136 + (ks2 + 1) * 32 + quad * 8];
#pragma unroll
      for (int nt = 0; nt < 8; ++nt)
        bvn[nt] = *(const bf16x8*)&vb[(size_t)(nt * 16 + l16) * T_ + sbase];
    }
#pragma unroll
    for (int nt = 0; nt < 8; ++nt)
      oacc[nt] = __builtin_amdgcn_mfma_f32_16x16x32_bf16(pa, bv[nt], oacc[nt], 0, 0, 0);
    pa = pan;
#pragma unroll
    for (int nt = 0; nt < 8; ++nt) bv[nt] = bvn[nt];
  }

  // ---- combine partials across the two parity waves of each tile
  if (par == 1) {
#pragma unroll
    for (int nt = 0; nt < 8; ++nt)
#pragma unroll
      for (int r = 0; r < 4; ++r)
        Olds[tile][quad * 4 + r][nt * 16 + l16] = oacc[nt][r];
    if (l16 == 0) {
#pragma unroll
      for (int r = 0; r < 4; ++r) rs1[tile][quad * 4 + r] = rsum[r];
    }
  }
  __syncthreads();
  if (par == 0) {
    float inv[4];
#pragma unroll
    for (int r = 0; r < 4; ++r)
      inv[r] = 1.f / (rsum[r] + rs1[tile][quad * 4 + r]);
    float* ob = out + ((size_t)b * T_ + t0) * HS_;
#pragma unroll
    for (int nt = 0; nt < 8; ++nt)
#pragma unroll
      for (int r = 0; r < 4; ++r) {
        int row = quad * 4 + r;
        ob[(size_t)row * HS_ + nt * 16 + l16] =
            (oacc[nt][r] + Olds[tile][row][nt * 16 + l16]) * inv[r];
      }
  }
}

extern "C" void kernel_launch(void* const* d_in, const int* in_sizes, int n_in,
                              void* d_out, int out_size, void* d_ws, size_t ws_size,
                              hipStream_t stream) {
  const float* x  = (const float*)d_in[0];
  const float* Wk = (const float*)d_in[1];
  const float* Wq = (const float*)d_in[2];
  const float* Wv = (const float*)d_in[3];
  float* out = (float*)d_out;

  char* ws = (char*)d_ws;
  unsigned short* Wt  = (unsigned short*)(ws);                        // 1.5 MB
  unsigned short* kqv = (unsigned short*)(ws + 1572864);              // 12 MB
  unsigned short* vT  = (unsigned short*)(ws + 1572864 + 12582912);   // 4 MB

  hipLaunchKernelGGL(wt_kernel, dim3(64, 4, 3), dim3(256), 0, stream, Wk, Wq, Wv, Wt);
  hipLaunchKernelGGL(qkv_gemm, dim3(512), dim3(256), 0, stream, x, Wt, kqv, vT);
  hipLaunchKernelGGL(attn_kernel, dim3(8, 64), dim3(256), 0, stream, kqv, vT, out);
}

// Round 6
// 284.786 us; speedup vs baseline: 1.1927x; 1.1927x over previous
//
#include <hip/hip_runtime.h>
#include <hip/hip_bf16.h>
#include <cstdint>
#include <cstddef>

#define B_  64
#define T_  256
#define C_  2048
#define HS_ 128
#define N_  384

typedef __bf16 bf16x8 __attribute__((ext_vector_type(8)));
typedef float  floatx4 __attribute__((ext_vector_type(4)));

__device__ __forceinline__ unsigned short f2bf_rne(float f) {
  union { float f; unsigned int u; } v; v.f = f;
  unsigned int r = v.u + 0x7fffu + ((v.u >> 16) & 1u);
  return (unsigned short)(r >> 16);
}
__device__ __forceinline__ unsigned short f2bf(float f) {
  union { float f; unsigned int u; } v; v.f = f;
  return (unsigned short)((v.u + 0x8000u) >> 16);
}

__device__ __forceinline__ void async_copy16(const void* g, void* l) {
  __builtin_amdgcn_global_load_lds(
      (const __attribute__((address_space(1))) unsigned int*)g,
      (__attribute__((address_space(3))) unsigned int*)l, 16, 0, 0);
}

// ---------------- Weight transpose + bf16 cast: Wt[w*128+h][c] = W_w[c][h] ---
__global__ __launch_bounds__(256) void wt_kernel(
    const float* __restrict__ Wk, const float* __restrict__ Wq,
    const float* __restrict__ Wv, unsigned short* __restrict__ Wt) {
  __shared__ float tile[32][33];
  const int w  = blockIdx.z;
  const int c0 = blockIdx.x * 32;
  const int h0 = blockIdx.y * 32;
  const float* W = (w == 0) ? Wk : (w == 1) ? Wq : Wv;
  const int tx = threadIdx.x & 31, ty = threadIdx.x >> 5;
#pragma unroll
  for (int i = 0; i < 32; i += 8)
    tile[ty + i][tx] = W[(size_t)(c0 + ty + i) * HS_ + h0 + tx];
  __syncthreads();
#pragma unroll
  for (int i = 0; i < 32; i += 8) {
    int hh = ty + i, cc = tx;
    Wt[(size_t)(w * HS_ + h0 + hh) * C_ + c0 + cc] = f2bf_rne(tile[cc][hh]);
  }
}

// ---------------- QKV GEMM: BM=64 x BN=192, BK=64, ring-3 counted-vmcnt -----
// Latency-serialization fix (rounds 0-5 post-mortem): ALL staging goes
// through global_load_lds into a 3-deep LDS ring (A staged as raw fp32,
// converted to bf16 at fragment-read time via hardware cvt). One barrier
// per K-step: "s_waitcnt vmcnt(10); s_barrier" -- vmcnt never drains to 0
// in the loop, each tile's 10 DMA instructions get ~2 iterations of
// latency cover (T3/T4 counted-vmcnt, m218 lever).
// Ring safety: at iter k the DMA targets buf((k+2)%3), which holds tile
// k-1; the barrier at iter k orders every wave past compute(k-1). Per-wave
// vmcnt(10) before the barrier ensures all waves' tile-k slices landed.
// LDS = 3 x (16 KB fp32-A + 24 KB bf16-B) = 120 KB dynamic, 1 block/CU.
// Chunk-xor swizzles applied on the DMA SOURCE address (LDS stays linear):
// A: chunk ^= (row&15) (fp32 row-major is the G4 bank trap otherwise);
// B: chunk ^= (row&7) (round-0-proven mapping).
__global__ __launch_bounds__(256) void qkv_gemm(
    const float* __restrict__ X, const unsigned short* __restrict__ Wt,
    unsigned short* __restrict__ kqv, unsigned short* __restrict__ vT) {
  extern __shared__ char smem[];        // 3 x 40960 B

  const int tid  = threadIdx.x;
  const int wave = tid >> 6, lane = tid & 63;
  const int quad = lane >> 4, l16 = lane & 15;

  const int bid = blockIdx.x;
  const int m0  = (bid & 255) * 64;     // bid and bid+256: same m -> same CU
  const int n0g = (bid >> 8) * 192;     // round 2 hits warm L2 for A
  const int wm  = (wave >> 1) * 32;     // {0,32}
  const int wn  = (wave & 1) * 96;      // {0,96}

  // ---- k-invariant DMA maps (source pre-swizzled, LDS linear)
  // A: 64 rows x 16 fp32-chunks(16B) = 1024 slots, 4/thread.
  const float* asrc[4]; int adst[4];
#pragma unroll
  for (int j = 0; j < 4; ++j) {
    int s = j * 256 + tid;
    int r = s >> 4, cd = s & 15, cs = cd ^ (r & 15);
    asrc[j] = X + (size_t)(m0 + r) * C_ + cs * 4;
    adst[j] = j * 4096 + wave * 1024;          // + lane*16 by HW
  }
  // B: 192 rows x 8 bf16-chunks(16B) = 1536 slots, 6/thread.
  const unsigned short* bsrc[6]; int bdst[6];
#pragma unroll
  for (int j = 0; j < 6; ++j) {
    int s = j * 256 + tid;
    int n = s >> 3, cd = s & 7, cs = cd ^ (n & 7);
    bsrc[j] = Wt + (size_t)(n0g + n) * C_ + cs * 8;
    bdst[j] = 16384 + j * 4096 + wave * 1024;
  }

#define ISSUE(KB, BASE)                                                        \
  {                                                                            \
    _Pragma("unroll")                                                          \
    for (int j = 0; j < 4; ++j)                                                \
      async_copy16(asrc[j] + (KB), smem + (BASE) + adst[j]);                   \
    _Pragma("unroll")                                                          \
    for (int j = 0; j < 6; ++j)                                                \
      async_copy16(bsrc[j] + (KB), smem + (BASE) + bdst[j]);                   \
  }

  floatx4 acc[2][6] = {};

#define COMPUTE(BASE)                                                          \
  {                                                                            \
    const char* ab = smem + (BASE);                                            \
    const char* bb = smem + (BASE) + 16384;                                    \
    _Pragma("unroll")                                                          \
    for (int ks = 0; ks < 2; ++ks) {                                           \
      bf16x8 af[2];                                                            \
      _Pragma("unroll")                                                        \
      for (int mt = 0; mt < 2; ++mt) {                                         \
        int r = wm + mt * 16 + l16;            /* r&15 == l16 */               \
        int cA = (ks * 8 + 2 * quad) ^ l16;    /* chunk of frag half 0 */      \
        float4 f0 = *(const float4*)(ab + r * 256 + cA * 16);                  \
        float4 f1 = *(const float4*)(ab + r * 256 + (cA ^ 1) * 16);            \
        union { __bf16 h[8]; bf16x8 v; } u;                                    \
        u.h[0] = (__bf16)f0.x; u.h[1] = (__bf16)f0.y;                          \
        u.h[2] = (__bf16)f0.z; u.h[3] = (__bf16)f0.w;                          \
        u.h[4] = (__bf16)f1.x; u.h[5] = (__bf16)f1.y;                          \
        u.h[6] = (__bf16)f1.z; u.h[7] = (__bf16)f1.w;                          \
        af[mt] = u.v;                                                          \
      }                                                                        \
      _Pragma("unroll")                                                        \
      for (int nt = 0; nt < 6; ++nt) {                                         \
        int n = wn + nt * 16 + l16;                                            \
        int c = (ks * 4 + quad) ^ (n & 7);                                     \
        bf16x8 bv = *(const bf16x8*)(bb + n * 128 + c * 16);                   \
        acc[0][nt] = __builtin_amdgcn_mfma_f32_16x16x32_bf16(                  \
            af[0], bv, acc[0][nt], 0, 0, 0);                                   \
        acc[1][nt] = __builtin_amdgcn_mfma_f32_16x16x32_bf16(                  \
            af[1], bv, acc[1][nt], 0, 0, 0);                                   \
      }                                                                        \
    }                                                                          \
  }

  // ---- prologue: tiles 0 and 1 in flight (20 DMA/wave)
  int off0 = 0, off1 = 40960, off2 = 81920;
  ISSUE(0, off0);
  ISSUE(64, off1);

  for (int k = 0; k < 32; ++k) {
    // tile k's 10 DMAs are the oldest; tile k+1's 10 may stay outstanding.
    asm volatile("s_waitcnt vmcnt(10)" ::: "memory");
    __builtin_amdgcn_s_barrier();
    __builtin_amdgcn_sched_barrier(0);
    // issue tile k+2 (clamped re-load of tile 31 keeps the count uniform;
    // target buffer is never read again in the tail)
    const int kt = (k + 2 < 32) ? (k + 2) : 31;
    ISSUE(kt * 64, off2);
    COMPUTE(off0);
    int t = off0; off0 = off1; off1 = off2; off2 = t;
  }
#undef ISSUE
#undef COMPUTE

  // ---- epilogue: C/D layout col=lane&15, row=quad*4+reg
#pragma unroll
  for (int mt = 0; mt < 2; ++mt)
#pragma unroll
    for (int nt = 0; nt < 6; ++nt)
#pragma unroll
      for (int r = 0; r < 4; ++r) {
        int row = m0 + wm + mt * 16 + quad * 4 + r;
        int col = n0g + wn + nt * 16 + l16;
        unsigned short us = f2bf(acc[mt][nt][r]);
        kqv[(size_t)row * N_ + col] = us;
        if (col >= 256) {   // V region -> also store transposed
          int bb2 = row >> 8, tt = row & 255;
          vT[(size_t)bb2 * HS_ * T_ + (size_t)(col - 256) * T_ + tt] = us;
        }
      }
}

// ---------------- Attention: 4 waves/block, 2 waves per 16-row t-tile -------
// Wave (tile, par): handles s-tiles st with st&1==par, packed densely in its
// private P buffer. Partial O (unnormalized) + partial rowsum combined in LDS.
// Tile pairing {x, 15-x}: every block carries an equal 17 units of causal
// work. (Part of the best 241.8 us config.)
__global__ __launch_bounds__(256) void attn_kernel(
    const unsigned short* __restrict__ kqv, const unsigned short* __restrict__ vT,
    float* __restrict__ out) {
  __shared__ unsigned short P[4][16 * 136];  // 17.4 KB, per-wave packed P
  __shared__ float Olds[2][16][132];         // 16.9 KB (pad 132)
  __shared__ float rs1[2][16];

  const int tid  = threadIdx.x;
  const int wave = tid >> 6, lane = tid & 63;
  const int quad = lane >> 4, l16 = lane & 15;
  const int tile = wave >> 1, par = wave & 1;
  const int tt = tile ? (15 - (int)blockIdx.x) : (int)blockIdx.x;  // balanced pair
  const int b  = blockIdx.y;
  const int t0 = tt * 16;
  const float scale = 0.022097086912079612f; // 2048^-0.5
  const unsigned short* kq = kqv + (size_t)b * T_ * N_;

  // k fragments (A operand), rows t0..t0+15
  bf16x8 kf[4];
#pragma unroll
  for (int ks = 0; ks < 4; ++ks)
    kf[ks] = *(const bf16x8*)&kq[(size_t)(t0 + l16) * N_ + ks * 32 + quad * 8];

  const int n_my = ((tt + 1) + (1 - par)) >> 1;  // my s-tile count
  const int npad = (n_my + 1) & ~1;              // padded to even

  float rsum[4] = {0.f, 0.f, 0.f, 0.f};

  // ---- S = k q^T over my s-tiles, exp+mask, pack into P (manual prefetch)
  bf16x8 qf[4];
  if (n_my > 0) {
    const int st = par;
#pragma unroll
    for (int ks = 0; ks < 4; ++ks)
      qf[ks] = *(const bf16x8*)&kq[(size_t)(st * 16 + l16) * N_ + HS_ + ks * 32 + quad * 8];
  }
  for (int j = 0; j < n_my; ++j) {
    bf16x8 qn[4];
    if (j + 1 < n_my) {
      const int st = par + 2 * (j + 1);
#pragma unroll
      for (int ks = 0; ks < 4; ++ks)
        qn[ks] = *(const bf16x8*)&kq[(size_t)(st * 16 + l16) * N_ + HS_ + ks * 32 + quad * 8];
    }
    floatx4 a = {};
#pragma unroll
    for (int ks = 0; ks < 4; ++ks)
      a = __builtin_amdgcn_mfma_f32_16x16x32_bf16(kf[ks], qf[ks], a, 0, 0, 0);
    const int st = par + 2 * j;
    const int scol = st * 16 + l16;
#pragma unroll
    for (int r = 0; r < 4; ++r) {
      int trow = t0 + quad * 4 + r;
      float p = (scol <= trow) ? __expf(a[r] * scale) : 0.f;
      rsum[r] += p;
      P[wave][(quad * 4 + r) * 136 + j * 16 + l16] = f2bf(p);
    }
#pragma unroll
    for (int ks = 0; ks < 4; ++ks) qf[ks] = qn[ks];
  }
  if (npad > n_my) {  // zero-fill the odd tail tile
#pragma unroll
    for (int r = 0; r < 4; ++r)
      P[wave][(quad * 4 + r) * 136 + n_my * 16 + l16] = 0;
  }
  // row sums: reduce across the 16 lanes of each quad
#pragma unroll
  for (int m = 1; m < 16; m <<= 1)
#pragma unroll
    for (int r = 0; r < 4; ++r)
      rsum[r] += __shfl_xor(rsum[r], m, 64);

  // ---- O_partial = P @ V over packed k-steps (manual prefetch)
  floatx4 oacc[8] = {};
  const unsigned short* vb = vT + (size_t)b * HS_ * T_;
  const int nks = npad >> 1;
  const int sb_off = (quad >> 1);        // which packed 16-tile inside 32-k
  const int sb_lo  = (quad & 1) * 8;
  bf16x8 bv[8]; bf16x8 pa;
  if (nks > 0) {
    int st = par + 2 * (0 + sb_off);
    int sbase = st * 16 + sb_lo;
    pa = *(const bf16x8*)&P[wave][l16 * 136 + 0 * 32 + quad * 8];
#pragma unroll
    for (int nt = 0; nt < 8; ++nt)
      bv[nt] = *(const bf16x8*)&vb[(size_t)(nt * 16 + l16) * T_ + sbase];
  }
  for (int ks2 = 0; ks2 < nks; ++ks2) {
    bf16x8 bvn[8]; bf16x8 pan;
    if (ks2 + 1 < nks) {
      int jt = 2 * (ks2 + 1) + sb_off;
      int st = par + 2 * jt;
      int sbase = st * 16 + sb_lo;
      pan = *(const bf16x8*)&P[wave][l16 * 136 + (ks2 + 1) * 32 + quad * 8];
#pragma unroll
      for (int nt = 0; nt < 8; ++nt)
        bvn[nt] = *(const bf16x8*)&vb[(size_t)(nt * 16 + l16) * T_ + sbase];
    }
#pragma unroll
    for (int nt = 0; nt < 8; ++nt)
      oacc[nt] = __builtin_amdgcn_mfma_f32_16x16x32_bf16(pa, bv[nt], oacc[nt], 0, 0, 0);
    pa = pan;
#pragma unroll
    for (int nt = 0; nt < 8; ++nt) bv[nt] = bvn[nt];
  }

  // ---- combine partials across the two parity waves of each tile
  if (par == 1) {
#pragma unroll
    for (int nt = 0; nt < 8; ++nt)
#pragma unroll
      for (int r = 0; r < 4; ++r)
        Olds[tile][quad * 4 + r][nt * 16 + l16] = oacc[nt][r];
    if (l16 == 0) {
#pragma unroll
      for (int r = 0; r < 4; ++r) rs1[tile][quad * 4 + r] = rsum[r];
    }
  }
  __syncthreads();
  if (par == 0) {
    float inv[4];
#pragma unroll
    for (int r = 0; r < 4; ++r)
      inv[r] = 1.f / (rsum[r] + rs1[tile][quad * 4 + r]);
    float* ob = out + ((size_t)b * T_ + t0) * HS_;
#pragma unroll
    for (int nt = 0; nt < 8; ++nt)
#pragma unroll
      for (int r = 0; r < 4; ++r) {
        int row = quad * 4 + r;
        ob[(size_t)row * HS_ + nt * 16 + l16] =
            (oacc[nt][r] + Olds[tile][row][nt * 16 + l16]) * inv[r];
      }
  }
}

extern "C" void kernel_launch(void* const* d_in, const int* in_sizes, int n_in,
                              void* d_out, int out_size, void* d_ws, size_t ws_size,
                              hipStream_t stream) {
  const float* x  = (const float*)d_in[0];
  const float* Wk = (const float*)d_in[1];
  const float* Wq = (const float*)d_in[2];
  const float* Wv = (const float*)d_in[3];
  float* out = (float*)d_out;

  char* ws = (char*)d_ws;
  unsigned short* Wt  = (unsigned short*)(ws);                        // 1.5 MB
  unsigned short* kqv = (unsigned short*)(ws + 1572864);              // 12 MB
  unsigned short* vT  = (unsigned short*)(ws + 1572864 + 12582912);   // 4 MB

  static bool attr_set = false;
  if (!attr_set) {
    (void)hipFuncSetAttribute(reinterpret_cast<const void*>(qkv_gemm),
                              hipFuncAttributeMaxDynamicSharedMemorySize,
                              122880);
    attr_set = true;
  }

  hipLaunchKernelGGL(wt_kernel, dim3(64, 4, 3), dim3(256), 0, stream, Wk, Wq, Wv, Wt);
  hipLaunchKernelGGL(qkv_gemm, dim3(512), dim3(256), 122880, stream, x, Wt, kqv, vT);
  hipLaunchKernelGGL(attn_kernel, dim3(8, 64), dim3(256), 0, stream, kqv, vT, out);
}

// Round 8
// 259.603 us; speedup vs baseline: 1.3084x; 1.0970x over previous
//
#include <hip/hip_runtime.h>
#include <hip/hip_bf16.h>
#include <cstdint>
#include <cstddef>

#define B_  64
#define T_  256
#define C_  2048
#define HS_ 128
#define N_  384

typedef __bf16 bf16x8 __attribute__((ext_vector_type(8)));
typedef float  floatx4 __attribute__((ext_vector_type(4)));

__device__ __forceinline__ unsigned short f2bf_rne(float f) {
  union { float f; unsigned int u; } v; v.f = f;
  unsigned int r = v.u + 0x7fffu + ((v.u >> 16) & 1u);
  return (unsigned short)(r >> 16);
}
__device__ __forceinline__ unsigned short f2bf(float f) {
  union { float f; unsigned int u; } v; v.f = f;
  return (unsigned short)((v.u + 0x8000u) >> 16);
}

__device__ __forceinline__ void async_copy16(const void* g, void* l) {
  __builtin_amdgcn_global_load_lds(
      (const __attribute__((address_space(1))) unsigned int*)g,
      (__attribute__((address_space(3))) unsigned int*)l, 16, 0, 0);
}

// ---------------- Weight transpose + bf16 cast: Wt[w*128+h][c] = W_w[c][h] ---
__global__ __launch_bounds__(256) void wt_kernel(
    const float* __restrict__ Wk, const float* __restrict__ Wq,
    const float* __restrict__ Wv, unsigned short* __restrict__ Wt) {
  __shared__ float tile[32][33];
  const int w  = blockIdx.z;
  const int c0 = blockIdx.x * 32;
  const int h0 = blockIdx.y * 32;
  const float* W = (w == 0) ? Wk : (w == 1) ? Wq : Wv;
  const int tx = threadIdx.x & 31, ty = threadIdx.x >> 5;
#pragma unroll
  for (int i = 0; i < 32; i += 8)
    tile[ty + i][tx] = W[(size_t)(c0 + ty + i) * HS_ + h0 + tx];
  __syncthreads();
#pragma unroll
  for (int i = 0; i < 32; i += 8) {
    int hh = ty + i, cc = tx;
    Wt[(size_t)(w * HS_ + h0 + hh) * C_ + c0 + cc] = f2bf_rne(tile[cc][hh]);
  }
}

// ---------------- QKV GEMM: 64m x 128n, BK=64 — ring-3 B + counted vmcnt ----
// R7 structure with the R7 BUG FIXED: ISSUE_B takes a TILE INDEX (macro
// multiplies by 64 shorts itself); R7's loop passed kt*64 -> B read 64x off,
// OOB into the workspace -> absmax 131. Loop now passes kt.
// Schedule (audited): B in a 3-deep DMA ring issued AFTER the barrier (no
// WAR: barrier k proves all waves past compute(k-1), the slot's last
// reader); A float4 loads one iter ahead, drained by vmcnt(4) (leaves only
// the newest B-DMA outstanding), f2bf'd into a xor-swizzled As dbuf.
// ONE barrier/iter; vmcnt never hits 0 inside the loop.
// Pending audit (steady state/wave): at barrier: B(k+1)4+A(k+1)4=8; after
// ISSUE_B(k+2): 12; vmcnt(4) leaves B(k+2). Prologue: vmcnt(8) twice
// establishes the invariant. Final vmcnt(0) drains tail DMA before retire.
// LDS: B ring 3x16 KB + A dbuf 2x8 KB = 65536 B dynamic -> 2 blocks/CU.
__global__ __launch_bounds__(256) void qkv_gemm(
    const float* __restrict__ X, const unsigned short* __restrict__ Wt,
    unsigned short* __restrict__ kqv, unsigned short* __restrict__ vT) {
  extern __shared__ char smem[];   // [0,49152): B ring; [49152,65536): A dbuf

  const int tid  = threadIdx.x;
  const int wave = tid >> 6, lane = tid & 63;
  const int quad = lane >> 4, l16 = lane & 15;

  const int g  = blockIdx.x;
  const int ml = g & 7, q8 = g >> 3;
  const int nb = q8 % 3, mh = q8 / 3;
  const int m0 = (mh * 8 + ml) * 64;
  const int n0 = nb * 128;
  const int wm = (wave >> 1) * 32;
  const int wn = (wave & 1) * 64;

  // B DMA map (R0's proven source-side xor swizzle): 128 rows x 8 chunks.
  const unsigned short* bsrc[4]; int bdst[4];
#pragma unroll
  for (int r = 0; r < 4; ++r) {
    int slot = (r * 4 + wave) * 64 + lane;
    int n = slot >> 3, sl = slot & 7;
    bsrc[r] = Wt + (size_t)(n0 + n) * C_ + (sl ^ (n & 7)) * 8;
    bdst[r] = (r * 4 + wave) * 1024;          // bytes; +lane*16 by HW
  }
  // A map: 64 rows x 16 float4-chunks = 1024 slots = 4/thread (coalesced).
  int arow[4], achk[4], awoff[4];
#pragma unroll
  for (int r = 0; r < 4; ++r) {
    int s = r * 256 + tid;
    arow[r] = s >> 4; achk[r] = s & 15;
    // xor-swizzled As byte offset: row*128 + ((chk>>1)^(row&7))*16 + (chk&1)*8
    awoff[r] = arow[r] * 128 + (((achk[r] >> 1) ^ (arow[r] & 7)) << 4) + ((achk[r] & 1) << 3);
  }

// KT is a TILE INDEX (64 shorts per K-step along a B row).
#define ISSUE_B(KT, OFF)                                                       \
  {                                                                            \
    _Pragma("unroll")                                                          \
    for (int r = 0; r < 4; ++r)                                                \
      async_copy16(bsrc[r] + (size_t)(KT) * 64, smem + (OFF) + bdst[r]);       \
  }
// KT is a TILE INDEX (64 floats per K-step along an X row).
#define LOAD_A(KT)                                                             \
  {                                                                            \
    _Pragma("unroll")                                                          \
    for (int r = 0; r < 4; ++r)                                                \
      av[r] = *(const float4*)(X + (size_t)(m0 + arow[r]) * C_ + (KT) * 64 + achk[r] * 4); \
  }
#define STORE_A(BUF)                                                           \
  {                                                                            \
    _Pragma("unroll")                                                          \
    for (int r = 0; r < 4; ++r) {                                              \
      ushort4 b4;                                                              \
      b4.x = f2bf(av[r].x); b4.y = f2bf(av[r].y);                              \
      b4.z = f2bf(av[r].z); b4.w = f2bf(av[r].w);                              \
      *(ushort4*)(smem + 49152 + (BUF) * 8192 + awoff[r]) = b4;                \
    }                                                                          \
  }

  floatx4 acc[2][4] = {};

#define COMPUTE(CUR, OFF)                                                      \
  {                                                                            \
    const char* ab = smem + 49152 + (CUR) * 8192;                              \
    const char* bb = smem + (OFF);                                             \
    _Pragma("unroll")                                                          \
    for (int ks = 0; ks < 2; ++ks) {                                           \
      bf16x8 af[2], bfv[4];                                                    \
      _Pragma("unroll")                                                        \
      for (int mt = 0; mt < 2; ++mt) {                                         \
        int rr = wm + mt * 16 + l16;                                           \
        af[mt] = *(const bf16x8*)(ab + rr * 128 + (((ks * 4 + quad) ^ (rr & 7)) << 4)); \
      }                                                                        \
      _Pragma("unroll")                                                        \
      for (int nt = 0; nt < 4; ++nt) {                                         \
        int n = wn + nt * 16 + l16;                                            \
        bfv[nt] = *(const bf16x8*)(bb + n * 128 + (((ks * 4 + quad) ^ (n & 7)) << 4)); \
      }                                                                        \
      _Pragma("unroll")                                                        \
      for (int mt = 0; mt < 2; ++mt)                                           \
        _Pragma("unroll")                                                      \
        for (int nt = 0; nt < 4; ++nt)                                         \
          acc[mt][nt] = __builtin_amdgcn_mfma_f32_16x16x32_bf16(               \
              af[mt], bfv[nt], acc[mt][nt], 0, 0, 0);                          \
    }                                                                          \
  }

  // ---- prologue: A(0) oldest -> vmcnt(8) leaves B(0),B(1) in flight.
  float4 av[4];
  LOAD_A(0);
  ISSUE_B(0, 0);
  ISSUE_B(1, 16384);
  asm volatile("s_waitcnt vmcnt(8)" ::: "memory");   // A(0) landed
  STORE_A(0);
  LOAD_A(1);                                          // pending: B0,B1,A1 = 12
  asm volatile("s_waitcnt vmcnt(8)" ::: "memory");   // B(0) landed (B1,A1 out)
  asm volatile("s_waitcnt lgkmcnt(0)" ::: "memory"); // As[0] stores done

  int off0 = 0, off1 = 16384, off2 = 32768;  // B(k), B(k+1), issue target

  for (int k = 0; k < 32; ++k) {
    const int cur = k & 1, nxt = cur ^ 1;
    __builtin_amdgcn_s_barrier();            // B(k)+As[cur] visible block-wide
    __builtin_amdgcn_sched_barrier(0);
    // issue B(k+2) into the slot of B(k-1): all waves proved past its last
    // read (compute(k-1)) by this barrier. Tail re-issues tile 31 into a
    // slot that is never read again.
    const int kt = (k + 2 < 32) ? (k + 2) : 31;
    ISSUE_B(kt, off2);                       // pending: B(k+1),A(k+1),B(k+2)=12
    COMPUTE(cur, off0);
    asm volatile("s_waitcnt vmcnt(4)" ::: "memory");  // A(k+1)+B(k+1) done
    if (k < 31) {
      STORE_A(nxt);                          // As[nxt]: last read compute(k-1)
      if (k < 30) LOAD_A(k + 2);             // pending: B(k+2) + A(k+2)
      asm volatile("s_waitcnt lgkmcnt(0)" ::: "memory");
    }
    int t = off0; off0 = off1; off1 = off2; off2 = t;
  }
  asm volatile("s_waitcnt vmcnt(0)" ::: "memory");   // drain tail DMA
#undef ISSUE_B
#undef LOAD_A
#undef STORE_A
#undef COMPUTE

  // ---- epilogue: C/D layout col=lane&15, row=quad*4+reg
#pragma unroll
  for (int mt = 0; mt < 2; ++mt)
#pragma unroll
    for (int nt = 0; nt < 4; ++nt)
#pragma unroll
      for (int r = 0; r < 4; ++r) {
        int row = m0 + wm + mt * 16 + quad * 4 + r;
        int col = wn + nt * 16 + l16;
        unsigned short us = f2bf(acc[mt][nt][r]);
        kqv[(size_t)row * N_ + n0 + col] = us;
        if (n0 == 256) {
          int bb = row >> 8, tt = row & 255;
          vT[(size_t)bb * HS_ * T_ + (size_t)col * T_ + tt] = us;
        }
      }
}

// ---------------- Attention: 4 waves/block, 2 waves per 16-row t-tile -------
// Wave (tile, par): handles s-tiles st with st&1==par, packed densely in its
// private P buffer. Partial O (unnormalized) + partial rowsum combined in LDS.
// Tile pairing {x, 15-x}: equal causal work per block. (Best-config attn.)
__global__ __launch_bounds__(256) void attn_kernel(
    const unsigned short* __restrict__ kqv, const unsigned short* __restrict__ vT,
    float* __restrict__ out) {
  __shared__ unsigned short P[4][16 * 136];  // 17.4 KB, per-wave packed P
  __shared__ float Olds[2][16][132];         // 16.9 KB (pad 132)
  __shared__ float rs1[2][16];

  const int tid  = threadIdx.x;
  const int wave = tid >> 6, lane = tid & 63;
  const int quad = lane >> 4, l16 = lane & 15;
  const int tile = wave >> 1, par = wave & 1;
  const int tt = tile ? (15 - (int)blockIdx.x) : (int)blockIdx.x;  // balanced pair
  const int b  = blockIdx.y;
  const int t0 = tt * 16;
  const float scale = 0.022097086912079612f; // 2048^-0.5
  const unsigned short* kq = kqv + (size_t)b * T_ * N_;

  // k fragments (A operand), rows t0..t0+15
  bf16x8 kf[4];
#pragma unroll
  for (int ks = 0; ks < 4; ++ks)
    kf[ks] = *(const bf16x8*)&kq[(size_t)(t0 + l16) * N_ + ks * 32 + quad * 8];

  const int n_my = ((tt + 1) + (1 - par)) >> 1;  // my s-tile count
  const int npad = (n_my + 1) & ~1;              // padded to even

  float rsum[4] = {0.f, 0.f, 0.f, 0.f};

  // ---- S = k q^T over my s-tiles, exp+mask, pack into P (manual prefetch)
  bf16x8 qf[4];
  if (n_my > 0) {
    const int st = par;
#pragma unroll
    for (int ks = 0; ks < 4; ++ks)
      qf[ks] = *(const bf16x8*)&kq[(size_t)(st * 16 + l16) * N_ + HS_ + ks * 32 + quad * 8];
  }
  for (int j = 0; j < n_my; ++j) {
    bf16x8 qn[4];
    if (j + 1 < n_my) {
      const int st = par + 2 * (j + 1);
#pragma unroll
      for (int ks = 0; ks < 4; ++ks)
        qn[ks] = *(const bf16x8*)&kq[(size_t)(st * 16 + l16) * N_ + HS_ + ks * 32 + quad * 8];
    }
    floatx4 a = {};
#pragma unroll
    for (int ks = 0; ks < 4; ++ks)
      a = __builtin_amdgcn_mfma_f32_16x16x32_bf16(kf[ks], qf[ks], a, 0, 0, 0);
    const int st = par + 2 * j;
    const int scol = st * 16 + l16;
#pragma unroll
    for (int r = 0; r < 4; ++r) {
      int trow = t0 + quad * 4 + r;
      float p = (scol <= trow) ? __expf(a[r] * scale) : 0.f;
      rsum[r] += p;
      P[wave][(quad * 4 + r) * 136 + j * 16 + l16] = f2bf(p);
    }
#pragma unroll
    for (int ks = 0; ks < 4; ++ks) qf[ks] = qn[ks];
  }
  if (npad > n_my) {  // zero-fill the odd tail tile
#pragma unroll
    for (int r = 0; r < 4; ++r)
      P[wave][(quad * 4 + r) * 136 + n_my * 16 + l16] = 0;
  }
  // row sums: reduce across the 16 lanes of each quad
#pragma unroll
  for (int m = 1; m < 16; m <<= 1)
#pragma unroll
    for (int r = 0; r < 4; ++r)
      rsum[r] += __shfl_xor(rsum[r], m, 64);

  // ---- O_partial = P @ V over packed k-steps (manual prefetch)
  floatx4 oacc[8] = {};
  const unsigned short* vb = vT + (size_t)b * HS_ * T_;
  const int nks = npad >> 1;
  const int sb_off = (quad >> 1);        // which packed 16-tile inside 32-k
  const int sb_lo  = (quad & 1) * 8;
  bf16x8 bv[8]; bf16x8 pa;
  if (nks > 0) {
    int st = par + 2 * (0 + sb_off);
    int sbase = st * 16 + sb_lo;
    pa = *(const bf16x8*)&P[wave][l16 * 136 + 0 * 32 + quad * 8];
#pragma unroll
    for (int nt = 0; nt < 8; ++nt)
      bv[nt] = *(const bf16x8*)&vb[(size_t)(nt * 16 + l16) * T_ + sbase];
  }
  for (int ks2 = 0; ks2 < nks; ++ks2) {
    bf16x8 bvn[8]; bf16x8 pan;
    if (ks2 + 1 < nks) {
      int jt = 2 * (ks2 + 1) + sb_off;
      int st = par + 2 * jt;
      int sbase = st * 16 + sb_lo;
      pan = *(const bf16x8*)&P[wave][l16 * 136 + (ks2 + 1) * 32 + quad * 8];
#pragma unroll
      for (int nt = 0; nt < 8; ++nt)
        bvn[nt] = *(const bf16x8*)&vb[(size_t)(nt * 16 + l16) * T_ + sbase];
    }
#pragma unroll
    for (int nt = 0; nt < 8; ++nt)
      oacc[nt] = __builtin_amdgcn_mfma_f32_16x16x32_bf16(pa, bv[nt], oacc[nt], 0, 0, 0);
    pa = pan;
#pragma unroll
    for (int nt = 0; nt < 8; ++nt) bv[nt] = bvn[nt];
  }

  // ---- combine partials across the two parity waves of each tile
  if (par == 1) {
#pragma unroll
    for (int nt = 0; nt < 8; ++nt)
#pragma unroll
      for (int r = 0; r < 4; ++r)
        Olds[tile][quad * 4 + r][nt * 16 + l16] = oacc[nt][r];
    if (l16 == 0) {
#pragma unroll
      for (int r = 0; r < 4; ++r) rs1[tile][quad * 4 + r] = rsum[r];
    }
  }
  __syncthreads();
  if (par == 0) {
    float inv[4];
#pragma unroll
    for (int r = 0; r < 4; ++r)
      inv[r] = 1.f / (rsum[r] + rs1[tile][quad * 4 + r]);
    float* ob = out + ((size_t)b * T_ + t0) * HS_;
#pragma unroll
    for (int nt = 0; nt < 8; ++nt)
#pragma unroll
      for (int r = 0; r < 4; ++r) {
        int row = quad * 4 + r;
        ob[(size_t)row * HS_ + nt * 16 + l16] =
            (oacc[nt][r] + Olds[tile][row][nt * 16 + l16]) * inv[r];
      }
  }
}

extern "C" void kernel_launch(void* const* d_in, const int* in_sizes, int n_in,
                              void* d_out, int out_size, void* d_ws, size_t ws_size,
                              hipStream_t stream) {
  const float* x  = (const float*)d_in[0];
  const float* Wk = (const float*)d_in[1];
  const float* Wq = (const float*)d_in[2];
  const float* Wv = (const float*)d_in[3];
  float* out = (float*)d_out;

  char* ws = (char*)d_ws;
  unsigned short* Wt  = (unsigned short*)(ws);                        // 1.5 MB
  unsigned short* kqv = (unsigned short*)(ws + 1572864);              // 12 MB
  unsigned short* vT  = (unsigned short*)(ws + 1572864 + 12582912);   // 4 MB

  static bool attr_set = false;
  if (!attr_set) {
    (void)hipFuncSetAttribute(reinterpret_cast<const void*>(qkv_gemm),
                              hipFuncAttributeMaxDynamicSharedMemorySize,
                              65536);
    attr_set = true;
  }

  hipLaunchKernelGGL(wt_kernel, dim3(64, 4, 3), dim3(256), 0, stream, Wk, Wq, Wv, Wt);
  hipLaunchKernelGGL(qkv_gemm, dim3(768), dim3(256), 65536, stream, x, Wt, kqv, vT);
  hipLaunchKernelGGL(attn_kernel, dim3(8, 64), dim3(256), 0, stream, kqv, vT, out);
}

// Round 9
// 247.861 us; speedup vs baseline: 1.3704x; 1.0474x over previous
//
#include <hip/hip_runtime.h>
#include <hip/hip_bf16.h>
#include <cstdint>
#include <cstddef>

#define B_  64
#define T_  256
#define C_  2048
#define HS_ 128
#define N_  384

typedef __bf16 bf16x8 __attribute__((ext_vector_type(8)));
typedef float  floatx4 __attribute__((ext_vector_type(4)));

__device__ __forceinline__ unsigned short f2bf_rne(float f) {
  union { float f; unsigned int u; } v; v.f = f;
  unsigned int r = v.u + 0x7fffu + ((v.u >> 16) & 1u);
  return (unsigned short)(r >> 16);
}
__device__ __forceinline__ unsigned short f2bf(float f) {
  union { float f; unsigned int u; } v; v.f = f;
  return (unsigned short)((v.u + 0x8000u) >> 16);
}

__device__ __forceinline__ void async_copy16(const void* g, void* l) {
  __builtin_amdgcn_global_load_lds(
      (const __attribute__((address_space(1))) unsigned int*)g,
      (__attribute__((address_space(3))) unsigned int*)l, 16, 0, 0);
}

// ---------------- Weight transpose + bf16 cast: Wt[w*128+h][c] = W_w[c][h] ---
__global__ __launch_bounds__(256) void wt_kernel(
    const float* __restrict__ Wk, const float* __restrict__ Wq,
    const float* __restrict__ Wv, unsigned short* __restrict__ Wt) {
  __shared__ float tile[32][33];
  const int w  = blockIdx.z;
  const int c0 = blockIdx.x * 32;
  const int h0 = blockIdx.y * 32;
  const float* W = (w == 0) ? Wk : (w == 1) ? Wq : Wv;
  const int tx = threadIdx.x & 31, ty = threadIdx.x >> 5;
#pragma unroll
  for (int i = 0; i < 32; i += 8)
    tile[ty + i][tx] = W[(size_t)(c0 + ty + i) * HS_ + h0 + tx];
  __syncthreads();
#pragma unroll
  for (int i = 0; i < 32; i += 8) {
    int hh = ty + i, cc = tx;
    Wt[(size_t)(w * HS_ + h0 + hh) * C_ + c0 + cc] = f2bf_rne(tile[cc][hh]);
  }
}

// ---------------- QKV GEMM: 64m x 96n, BK=64 — 4 blocks/CU occupancy A/B ----
// R0's EXACT proven schedule (store-A -> one __syncthreads -> issue B-DMA +
// A-loads -> compute; compiler-managed waitcnts), geometry retuned for max
// residency: grid 1024 = 4 blocks/CU, LDS exactly 40960 B/block
// (As dbuf 16K xor-swizzled [R8-verified write/read pair] + Bs dbuf 24K
// source-swizzled DMA). 16 waves/CU in 4 INDEPENDENT barrier groups: while
// one block drains its barrier vmcnt, three others have runnable waves.
// Per-CU work/slot unchanged vs R0/R3 (4 x 0.39M MAC) -- this isolates the
// occupancy/latency-coverage axis.
__global__ __launch_bounds__(256, 4) void qkv_gemm(
    const float* __restrict__ X, const unsigned short* __restrict__ Wt,
    unsigned short* __restrict__ kqv, unsigned short* __restrict__ vT) {
  __shared__ unsigned short As[2][64 * 64];   // 16 KB, xor-swizzled
  __shared__ unsigned short Bs[2][96 * 64];   // 24 KB, source-swizzled DMA

  const int tid  = threadIdx.x;
  const int wave = tid >> 6, lane = tid & 63;
  const int quad = lane >> 4, l16 = lane & 15;

  // g = mh*32 + nb*8 + ml: 8 m-panels cycle innermost -> the 4 n-variants of
  // an m-panel land on the same XCD (round-robin mod 8) -> A re-reads L2-hot.
  const int g  = blockIdx.x;
  const int ml = g & 7;
  const int nb = (g >> 3) & 3;
  const int mh = g >> 5;
  const int m0 = (mh * 8 + ml) * 64;
  const int n0 = nb * 96;
  const int wm = (wave >> 1) * 32;    // {0,32}
  const int wn = (wave & 1) * 48;     // {0,48}

  // B DMA map: 96 rows x 8 chunks(16B) = 768 slots = 3/thread.
  // Source chunk xor-swizzled so reads de-swizzle conflict-spread.
  const unsigned short* bsrc[3]; int bdst[3];
#pragma unroll
  for (int r = 0; r < 3; ++r) {
    int s = r * 256 + tid;
    int n = s >> 3, sl = s & 7;
    bsrc[r] = Wt + (size_t)(n0 + n) * C_ + (sl ^ (n & 7)) * 8;
    bdst[r] = (r * 256 + wave * 64) * 8;   // short idx; +lane*16B by HW
  }
  // A map: 64 rows x 16 float4-chunks = 1024 slots = 4/thread (coalesced).
  int arow[4], achk[4], awoff[4];
#pragma unroll
  for (int r = 0; r < 4; ++r) {
    int s = r * 256 + tid;
    arow[r] = s >> 4; achk[r] = s & 15;
    // xor-swizzled As short idx: row*64 + ((chk>>1 ^ (row&7))<<3) + (chk&1)*4
    awoff[r] = arow[r] * 64 + (((achk[r] >> 1) ^ (arow[r] & 7)) << 3) + ((achk[r] & 1) << 2);
  }

  // ---- prologue: B_0 DMA + A_0 global loads
#pragma unroll
  for (int r = 0; r < 3; ++r)
    async_copy16(bsrc[r], &Bs[0][bdst[r]]);
  float4 av[4];
#pragma unroll
  for (int r = 0; r < 4; ++r)
    av[r] = *(const float4*)(X + (size_t)(m0 + arow[r]) * C_ + achk[r] * 4);

  floatx4 acc[2][3] = {};

  for (int k = 0; k < 32; ++k) {
    const int cur = k & 1, nxt = cur ^ 1;
    // ---- convert & store A_k into swizzled As[cur]
#pragma unroll
    for (int r = 0; r < 4; ++r) {
      ushort4 b4;
      b4.x = f2bf(av[r].x); b4.y = f2bf(av[r].y);
      b4.z = f2bf(av[r].z); b4.w = f2bf(av[r].w);
      *(ushort4*)&As[cur][awoff[r]] = b4;
    }
    __syncthreads();   // drains B_k DMA (issued last iter) + As stores

    // ---- issue next iteration's loads (a full iteration of latency cover)
    if (k < 31) {
      const int kn = (k + 1) * 64;
#pragma unroll
      for (int r = 0; r < 3; ++r)
        async_copy16(bsrc[r] + kn, &Bs[nxt][bdst[r]]);
#pragma unroll
      for (int r = 0; r < 4; ++r)
        av[r] = *(const float4*)(X + (size_t)(m0 + arow[r]) * C_ + kn + achk[r] * 4);
    }

    // ---- compute: 12 MFMAs/wave (2 ks x 2m x 3n)
#pragma unroll
    for (int ks = 0; ks < 2; ++ks) {
      bf16x8 af[2], bfv[3];
#pragma unroll
      for (int mt = 0; mt < 2; ++mt) {
        int rr = wm + mt * 16 + l16;
        af[mt] = *(const bf16x8*)&As[cur][rr * 64 + (((ks * 4 + quad) ^ (rr & 7)) << 3)];
      }
#pragma unroll
      for (int nt = 0; nt < 3; ++nt) {
        int n = wn + nt * 16 + l16;
        bfv[nt] = *(const bf16x8*)&Bs[cur][n * 64 + (((ks * 4 + quad) ^ (n & 7)) << 3)];
      }
#pragma unroll
      for (int mt = 0; mt < 2; ++mt)
#pragma unroll
        for (int nt = 0; nt < 3; ++nt)
          acc[mt][nt] = __builtin_amdgcn_mfma_f32_16x16x32_bf16(
              af[mt], bfv[nt], acc[mt][nt], 0, 0, 0);
    }
  }

  // ---- epilogue: C/D layout col=lane&15, row=quad*4+reg
#pragma unroll
  for (int mt = 0; mt < 2; ++mt)
#pragma unroll
    for (int nt = 0; nt < 3; ++nt)
#pragma unroll
      for (int r = 0; r < 4; ++r) {
        int row = m0 + wm + mt * 16 + quad * 4 + r;
        int col = n0 + wn + nt * 16 + l16;
        unsigned short us = f2bf(acc[mt][nt][r]);
        kqv[(size_t)row * N_ + col] = us;
        if (col >= 256) {   // V region -> also store transposed
          int bb = row >> 8, tt = row & 255;
          vT[(size_t)bb * HS_ * T_ + (size_t)(col - 256) * T_ + tt] = us;
        }
      }
}

// ---------------- Attention: 4 waves/block, 2 waves per 16-row t-tile -------
// Wave (tile, par): handles s-tiles st with st&1==par, packed densely in its
// private P buffer. Partial O (unnormalized) + partial rowsum combined in LDS.
// Tile pairing {x, 15-x}: equal causal work per block. (Best-config attn.)
__global__ __launch_bounds__(256) void attn_kernel(
    const unsigned short* __restrict__ kqv, const unsigned short* __restrict__ vT,
    float* __restrict__ out) {
  __shared__ unsigned short P[4][16 * 136];  // 17.4 KB, per-wave packed P
  __shared__ float Olds[2][16][132];         // 16.9 KB (pad 132)
  __shared__ float rs1[2][16];

  const int tid  = threadIdx.x;
  const int wave = tid >> 6, lane = tid & 63;
  const int quad = lane >> 4, l16 = lane & 15;
  const int tile = wave >> 1, par = wave & 1;
  const int tt = tile ? (15 - (int)blockIdx.x) : (int)blockIdx.x;  // balanced pair
  const int b  = blockIdx.y;
  const int t0 = tt * 16;
  const float scale = 0.022097086912079612f; // 2048^-0.5
  const unsigned short* kq = kqv + (size_t)b * T_ * N_;

  // k fragments (A operand), rows t0..t0+15
  bf16x8 kf[4];
#pragma unroll
  for (int ks = 0; ks < 4; ++ks)
    kf[ks] = *(const bf16x8*)&kq[(size_t)(t0 + l16) * N_ + ks * 32 + quad * 8];

  const int n_my = ((tt + 1) + (1 - par)) >> 1;  // my s-tile count
  const int npad = (n_my + 1) & ~1;              // padded to even

  float rsum[4] = {0.f, 0.f, 0.f, 0.f};

  // ---- S = k q^T over my s-tiles, exp+mask, pack into P (manual prefetch)
  bf16x8 qf[4];
  if (n_my > 0) {
    const int st = par;
#pragma unroll
    for (int ks = 0; ks < 4; ++ks)
      qf[ks] = *(const bf16x8*)&kq[(size_t)(st * 16 + l16) * N_ + HS_ + ks * 32 + quad * 8];
  }
  for (int j = 0; j < n_my; ++j) {
    bf16x8 qn[4];
    if (j + 1 < n_my) {
      const int st = par + 2 * (j + 1);
#pragma unroll
      for (int ks = 0; ks < 4; ++ks)
        qn[ks] = *(const bf16x8*)&kq[(size_t)(st * 16 + l16) * N_ + HS_ + ks * 32 + quad * 8];
    }
    floatx4 a = {};
#pragma unroll
    for (int ks = 0; ks < 4; ++ks)
      a = __builtin_amdgcn_mfma_f32_16x16x32_bf16(kf[ks], qf[ks], a, 0, 0, 0);
    const int st = par + 2 * j;
    const int scol = st * 16 + l16;
#pragma unroll
    for (int r = 0; r < 4; ++r) {
      int trow = t0 + quad * 4 + r;
      float p = (scol <= trow) ? __expf(a[r] * scale) : 0.f;
      rsum[r] += p;
      P[wave][(quad * 4 + r) * 136 + j * 16 + l16] = f2bf(p);
    }
#pragma unroll
    for (int ks = 0; ks < 4; ++ks) qf[ks] = qn[ks];
  }
  if (npad > n_my) {  // zero-fill the odd tail tile
#pragma unroll
    for (int r = 0; r < 4; ++r)
      P[wave][(quad * 4 + r) * 136 + n_my * 16 + l16] = 0;
  }
  // row sums: reduce across the 16 lanes of each quad
#pragma unroll
  for (int m = 1; m < 16; m <<= 1)
#pragma unroll
    for (int r = 0; r < 4; ++r)
      rsum[r] += __shfl_xor(rsum[r], m, 64);

  // ---- O_partial = P @ V over packed k-steps (manual prefetch)
  floatx4 oacc[8] = {};
  const unsigned short* vb = vT + (size_t)b * HS_ * T_;
  const int nks = npad >> 1;
  const int sb_off = (quad >> 1);        // which packed 16-tile inside 32-k
  const int sb_lo  = (quad & 1) * 8;
  bf16x8 bv[8]; bf16x8 pa;
  if (nks > 0) {
    int st = par + 2 * (0 + sb_off);
    int sbase = st * 16 + sb_lo;
    pa = *(const bf16x8*)&P[wave][l16 * 136 + 0 * 32 + quad * 8];
#pragma unroll
    for (int nt = 0; nt < 8; ++nt)
      bv[nt] = *(const bf16x8*)&vb[(size_t)(nt * 16 + l16) * T_ + sbase];
  }
  for (int ks2 = 0; ks2 < nks; ++ks2) {
    bf16x8 bvn[8]; bf16x8 pan;
    if (ks2 + 1 < nks) {
      int jt = 2 * (ks2 + 1) + sb_off;
      int st = par + 2 * jt;
      int sbase = st * 16 + sb_lo;
      pan = *(const bf16x8*)&P[wave][l16 * 136 + (ks2 + 1) * 32 + quad * 8];
#pragma unroll
      for (int nt = 0; nt < 8; ++nt)
        bvn[nt] = *(const bf16x8*)&vb[(size_t)(nt * 16 + l16) * T_ + sbase];
    }
#pragma unroll
    for (int nt = 0; nt < 8; ++nt)
      oacc[nt] = __builtin_amdgcn_mfma_f32_16x16x32_bf16(pa, bv[nt], oacc[nt], 0, 0, 0);
    pa = pan;
#pragma unroll
    for (int nt = 0; nt < 8; ++nt) bv[nt] = bvn[nt];
  }

  // ---- combine partials across the two parity waves of each tile
  if (par == 1) {
#pragma unroll
    for (int nt = 0; nt < 8; ++nt)
#pragma unroll
      for (int r = 0; r < 4; ++r)
        Olds[tile][quad * 4 + r][nt * 16 + l16] = oacc[nt][r];
    if (l16 == 0) {
#pragma unroll
      for (int r = 0; r < 4; ++r) rs1[tile][quad * 4 + r] = rsum[r];
    }
  }
  __syncthreads();
  if (par == 0) {
    float inv[4];
#pragma unroll
    for (int r = 0; r < 4; ++r)
      inv[r] = 1.f / (rsum[r] + rs1[tile][quad * 4 + r]);
    float* ob = out + ((size_t)b * T_ + t0) * HS_;
#pragma unroll
    for (int nt = 0; nt < 8; ++nt)
#pragma unroll
      for (int r = 0; r < 4; ++r) {
        int row = quad * 4 + r;
        ob[(size_t)row * HS_ + nt * 16 + l16] =
            (oacc[nt][r] + Olds[tile][row][nt * 16 + l16]) * inv[r];
      }
  }
}

extern "C" void kernel_launch(void* const* d_in, const int* in_sizes, int n_in,
                              void* d_out, int out_size, void* d_ws, size_t ws_size,
                              hipStream_t stream) {
  const float* x  = (const float*)d_in[0];
  const float* Wk = (const float*)d_in[1];
  const float* Wq = (const float*)d_in[2];
  const float* Wv = (const float*)d_in[3];
  float* out = (float*)d_out;

  char* ws = (char*)d_ws;
  unsigned short* Wt  = (unsigned short*)(ws);                        // 1.5 MB
  unsigned short* kqv = (unsigned short*)(ws + 1572864);              // 12 MB
  unsigned short* vT  = (unsigned short*)(ws + 1572864 + 12582912);   // 4 MB

  hipLaunchKernelGGL(wt_kernel, dim3(64, 4, 3), dim3(256), 0, stream, Wk, Wq, Wv, Wt);
  hipLaunchKernelGGL(qkv_gemm, dim3(1024), dim3(256), 0, stream, x, Wt, kqv, vT);
  hipLaunchKernelGGL(attn_kernel, dim3(8, 64), dim3(256), 0, stream, kqv, vT, out);
}

// Round 10
// 232.033 us; speedup vs baseline: 1.4638x; 1.0682x over previous
//
#include <hip/hip_runtime.h>
#include <hip/hip_bf16.h>
#include <cstdint>
#include <cstddef>

#define B_  64
#define T_  256
#define C_  2048
#define HS_ 128
#define N_  384

typedef __bf16 bf16x8 __attribute__((ext_vector_type(8)));
typedef float  floatx4 __attribute__((ext_vector_type(4)));

__device__ __forceinline__ unsigned short f2bf_rne(float f) {
  union { float f; unsigned int u; } v; v.f = f;
  unsigned int r = v.u + 0x7fffu + ((v.u >> 16) & 1u);
  return (unsigned short)(r >> 16);
}
__device__ __forceinline__ unsigned short f2bf(float f) {
  union { float f; unsigned int u; } v; v.f = f;
  return (unsigned short)((v.u + 0x8000u) >> 16);
}

__device__ __forceinline__ void async_copy16(const void* g, void* l) {
  __builtin_amdgcn_global_load_lds(
      (const __attribute__((address_space(1))) unsigned int*)g,
      (__attribute__((address_space(3))) unsigned int*)l, 16, 0, 0);
}

// ---------------- Weight transpose + bf16 cast: Wt[w*128+h][c] = W_w[c][h] ---
__global__ __launch_bounds__(256) void wt_kernel(
    const float* __restrict__ Wk, const float* __restrict__ Wq,
    const float* __restrict__ Wv, unsigned short* __restrict__ Wt) {
  __shared__ float tile[32][33];
  const int w  = blockIdx.z;
  const int c0 = blockIdx.x * 32;
  const int h0 = blockIdx.y * 32;
  const float* W = (w == 0) ? Wk : (w == 1) ? Wq : Wv;
  const int tx = threadIdx.x & 31, ty = threadIdx.x >> 5;
#pragma unroll
  for (int i = 0; i < 32; i += 8)
    tile[ty + i][tx] = W[(size_t)(c0 + ty + i) * HS_ + h0 + tx];
  __syncthreads();
#pragma unroll
  for (int i = 0; i < 32; i += 8) {
    int hh = ty + i, cc = tx;
    Wt[(size_t)(w * HS_ + h0 + hh) * C_ + c0 + cc] = f2bf_rne(tile[cc][hh]);
  }
}

// ---------------- QKV GEMM: BM=64 x BN=384 (full N), BK=64, 8 waves ---------
// Model from R0-R9 fit: wall_iter ~ 3000 cy fixed + perCU_bytes/29 B/cy;
// occupancy null (R9), counted-vmcnt null (R8), tile shuffles null (R3).
// Levers: wall-iteration count (keep 32) and TOTAL BYTES (805 -> 536 MB:
// A read exactly once at BN=384; B unchanged, L2-resident). Schedule is the
// R0/R9-proven one VERBATIM (store-A -> one __syncthreads -> issue B-DMA +
// A-loads -> compute; compiler-managed waits), re-indexed for 512 threads.
// Grid 256 = 1 block/CU. LDS: Bs dbuf 2x48K + As dbuf 2x8K = 112 KB dynamic.
// Wave grid 2m x 4n, wave tile 32x96, 24 MFMA/iter/wave (R3-proven load).
__global__ __launch_bounds__(512) void qkv_gemm(
    const float* __restrict__ X, const unsigned short* __restrict__ Wt,
    unsigned short* __restrict__ kqv, unsigned short* __restrict__ vT) {
  extern __shared__ char smem[];  // [0,98304): Bs dbuf; [98304,114688): As dbuf

  const int tid  = threadIdx.x;
  const int wave = tid >> 6, lane = tid & 63;
  const int quad = lane >> 4, l16 = lane & 15;

  const int m0 = blockIdx.x * 64;      // 256 blocks x 64 rows = M
  const int wm = (wave >> 2) * 32;     // {0,32}
  const int wn = (wave & 3) * 96;      // {0,96,192,288}

  // B DMA map: 384 rows x 8 chunks(16B) = 3072 slots = 6/thread.
  // Source chunk xor-swizzled (R0/R9-proven pair with the read below).
  const unsigned short* bsrc[6]; int bdst[6];
#pragma unroll
  for (int r = 0; r < 6; ++r) {
    int s = r * 512 + tid;
    int n = s >> 3, sl = s & 7;
    bsrc[r] = Wt + (size_t)n * C_ + (sl ^ (n & 7)) * 8;
    bdst[r] = (r * 512 + wave * 64) * 16;   // byte offset; +lane*16 by HW
  }
  // A map: 64 rows x 16 float4-chunks = 1024 slots = 2/thread (coalesced).
  int arow[2], achk[2], awoff[2];
#pragma unroll
  for (int r = 0; r < 2; ++r) {
    int s = r * 512 + tid;
    arow[r] = s >> 4; achk[r] = s & 15;
    // xor-swizzled As short idx (R9-verified write/read pair)
    awoff[r] = arow[r] * 64 + (((achk[r] >> 1) ^ (arow[r] & 7)) << 3) + ((achk[r] & 1) << 2);
  }

  // ---- prologue: B_0 DMA + A_0 global loads
#pragma unroll
  for (int r = 0; r < 6; ++r)
    async_copy16(bsrc[r], smem + bdst[r]);
  float4 av[2];
#pragma unroll
  for (int r = 0; r < 2; ++r)
    av[r] = *(const float4*)(X + (size_t)(m0 + arow[r]) * C_ + achk[r] * 4);

  floatx4 acc[2][6] = {};

  for (int k = 0; k < 32; ++k) {
    const int cur = k & 1, nxt = cur ^ 1;
    // ---- convert & store A_k into swizzled As[cur] (drains av: vmcnt(0))
    unsigned short* As = (unsigned short*)(smem + 98304 + cur * 8192);
#pragma unroll
    for (int r = 0; r < 2; ++r) {
      ushort4 b4;
      b4.x = f2bf(av[r].x); b4.y = f2bf(av[r].y);
      b4.z = f2bf(av[r].z); b4.w = f2bf(av[r].w);
      *(ushort4*)&As[awoff[r]] = b4;
    }
    __syncthreads();   // B_k DMA (issued last iter) + As stores visible

    // ---- issue next iteration's loads (a full iteration of latency cover)
    if (k < 31) {
      const int kn = (k + 1) * 64;
#pragma unroll
      for (int r = 0; r < 6; ++r)
        async_copy16(bsrc[r] + kn, smem + nxt * 49152 + bdst[r]);
#pragma unroll
      for (int r = 0; r < 2; ++r)
        av[r] = *(const float4*)(X + (size_t)(m0 + arow[r]) * C_ + kn + achk[r] * 4);
    }

    // ---- compute: 24 MFMAs/wave (2 ks x 2m x 6n)
    const unsigned short* Bsr = (const unsigned short*)(smem + cur * 49152);
#pragma unroll
    for (int ks = 0; ks < 2; ++ks) {
      bf16x8 af[2], bfv[6];
#pragma unroll
      for (int mt = 0; mt < 2; ++mt) {
        int rr = wm + mt * 16 + l16;
        af[mt] = *(const bf16x8*)&As[rr * 64 + (((ks * 4 + quad) ^ (rr & 7)) << 3)];
      }
#pragma unroll
      for (int nt = 0; nt < 6; ++nt) {
        int n = wn + nt * 16 + l16;
        bfv[nt] = *(const bf16x8*)&Bsr[n * 64 + (((ks * 4 + quad) ^ (n & 7)) << 3)];
      }
#pragma unroll
      for (int mt = 0; mt < 2; ++mt)
#pragma unroll
        for (int nt = 0; nt < 6; ++nt)
          acc[mt][nt] = __builtin_amdgcn_mfma_f32_16x16x32_bf16(
              af[mt], bfv[nt], acc[mt][nt], 0, 0, 0);
    }
  }

  // ---- epilogue: C/D layout col=lane&15, row=quad*4+reg
#pragma unroll
  for (int mt = 0; mt < 2; ++mt)
#pragma unroll
    for (int nt = 0; nt < 6; ++nt)
#pragma unroll
      for (int r = 0; r < 4; ++r) {
        int row = m0 + wm + mt * 16 + quad * 4 + r;
        int col = wn + nt * 16 + l16;
        unsigned short us = f2bf(acc[mt][nt][r]);
        kqv[(size_t)row * N_ + col] = us;
        if (col >= 256) {   // V region -> also store transposed
          int bb = row >> 8, tt = row & 255;
          vT[(size_t)bb * HS_ * T_ + (size_t)(col - 256) * T_ + tt] = us;
        }
      }
}

// ---------------- Attention: 4 waves/block, 2 waves per 16-row t-tile -------
// Wave (tile, par): handles s-tiles st with st&1==par, packed densely in its
// private P buffer. Partial O (unnormalized) + partial rowsum combined in LDS.
// Tile pairing {x, 15-x}: equal causal work per block. (Best-config attn.)
__global__ __launch_bounds__(256) void attn_kernel(
    const unsigned short* __restrict__ kqv, const unsigned short* __restrict__ vT,
    float* __restrict__ out) {
  __shared__ unsigned short P[4][16 * 136];  // 17.4 KB, per-wave packed P
  __shared__ float Olds[2][16][132];         // 16.9 KB (pad 132)
  __shared__ float rs1[2][16];

  const int tid  = threadIdx.x;
  const int wave = tid >> 6, lane = tid & 63;
  const int quad = lane >> 4, l16 = lane & 15;
  const int tile = wave >> 1, par = wave & 1;
  const int tt = tile ? (15 - (int)blockIdx.x) : (int)blockIdx.x;  // balanced pair
  const int b  = blockIdx.y;
  const int t0 = tt * 16;
  const float scale = 0.022097086912079612f; // 2048^-0.5
  const unsigned short* kq = kqv + (size_t)b * T_ * N_;

  // k fragments (A operand), rows t0..t0+15
  bf16x8 kf[4];
#pragma unroll
  for (int ks = 0; ks < 4; ++ks)
    kf[ks] = *(const bf16x8*)&kq[(size_t)(t0 + l16) * N_ + ks * 32 + quad * 8];

  const int n_my = ((tt + 1) + (1 - par)) >> 1;  // my s-tile count
  const int npad = (n_my + 1) & ~1;              // padded to even

  float rsum[4] = {0.f, 0.f, 0.f, 0.f};

  // ---- S = k q^T over my s-tiles, exp+mask, pack into P (manual prefetch)
  bf16x8 qf[4];
  if (n_my > 0) {
    const int st = par;
#pragma unroll
    for (int ks = 0; ks < 4; ++ks)
      qf[ks] = *(const bf16x8*)&kq[(size_t)(st * 16 + l16) * N_ + HS_ + ks * 32 + quad * 8];
  }
  for (int j = 0; j < n_my; ++j) {
    bf16x8 qn[4];
    if (j + 1 < n_my) {
      const int st = par + 2 * (j + 1);
#pragma unroll
      for (int ks = 0; ks < 4; ++ks)
        qn[ks] = *(const bf16x8*)&kq[(size_t)(st * 16 + l16) * N_ + HS_ + ks * 32 + quad * 8];
    }
    floatx4 a = {};
#pragma unroll
    for (int ks = 0; ks < 4; ++ks)
      a = __builtin_amdgcn_mfma_f32_16x16x32_bf16(kf[ks], qf[ks], a, 0, 0, 0);
    const int st = par + 2 * j;
    const int scol = st * 16 + l16;
#pragma unroll
    for (int r = 0; r < 4; ++r) {
      int trow = t0 + quad * 4 + r;
      float p = (scol <= trow) ? __expf(a[r] * scale) : 0.f;
      rsum[r] += p;
      P[wave][(quad * 4 + r) * 136 + j * 16 + l16] = f2bf(p);
    }
#pragma unroll
    for (int ks = 0; ks < 4; ++ks) qf[ks] = qn[ks];
  }
  if (npad > n_my) {  // zero-fill the odd tail tile
#pragma unroll
    for (int r = 0; r < 4; ++r)
      P[wave][(quad * 4 + r) * 136 + n_my * 16 + l16] = 0;
  }
  // row sums: reduce across the 16 lanes of each quad
#pragma unroll
  for (int m = 1; m < 16; m <<= 1)
#pragma unroll
    for (int r = 0; r < 4; ++r)
      rsum[r] += __shfl_xor(rsum[r], m, 64);

  // ---- O_partial = P @ V over packed k-steps (manual prefetch)
  floatx4 oacc[8] = {};
  const unsigned short* vb = vT + (size_t)b * HS_ * T_;
  const int nks = npad >> 1;
  const int sb_off = (quad >> 1);        // which packed 16-tile inside 32-k
  const int sb_lo  = (quad & 1) * 8;
  bf16x8 bv[8]; bf16x8 pa;
  if (nks > 0) {
    int st = par + 2 * (0 + sb_off);
    int sbase = st * 16 + sb_lo;
    pa = *(const bf16x8*)&P[wave][l16 * 136 + 0 * 32 + quad * 8];
#pragma unroll
    for (int nt = 0; nt < 8; ++nt)
      bv[nt] = *(const bf16x8*)&vb[(size_t)(nt * 16 + l16) * T_ + sbase];
  }
  for (int ks2 = 0; ks2 < nks; ++ks2) {
    bf16x8 bvn[8]; bf16x8 pan;
    if (ks2 + 1 < nks) {
      int jt = 2 * (ks2 + 1) + sb_off;
      int st = par + 2 * jt;
      int sbase = st * 16 + sb_lo;
      pan = *(const bf16x8*)&P[wave][l16 * 136 + (ks2 + 1) * 32 + quad * 8];
#pragma unroll
      for (int nt = 0; nt < 8; ++nt)
        bvn[nt] = *(const bf16x8*)&vb[(size_t)(nt * 16 + l16) * T_ + sbase];
    }
#pragma unroll
    for (int nt = 0; nt < 8; ++nt)
      oacc[nt] = __builtin_amdgcn_mfma_f32_16x16x32_bf16(pa, bv[nt], oacc[nt], 0, 0, 0);
    pa = pan;
#pragma unroll
    for (int nt = 0; nt < 8; ++nt) bv[nt] = bvn[nt];
  }

  // ---- combine partials across the two parity waves of each tile
  if (par == 1) {
#pragma unroll
    for (int nt = 0; nt < 8; ++nt)
#pragma unroll
      for (int r = 0; r < 4; ++r)
        Olds[tile][quad * 4 + r][nt * 16 + l16] = oacc[nt][r];
    if (l16 == 0) {
#pragma unroll
      for (int r = 0; r < 4; ++r) rs1[tile][quad * 4 + r] = rsum[r];
    }
  }
  __syncthreads();
  if (par == 0) {
    float inv[4];
#pragma unroll
    for (int r = 0; r < 4; ++r)
      inv[r] = 1.f / (rsum[r] + rs1[tile][quad * 4 + r]);
    float* ob = out + ((size_t)b * T_ + t0) * HS_;
#pragma unroll
    for (int nt = 0; nt < 8; ++nt)
#pragma unroll
      for (int r = 0; r < 4; ++r) {
        int row = quad * 4 + r;
        ob[(size_t)row * HS_ + nt * 16 + l16] =
            (oacc[nt][r] + Olds[tile][row][nt * 16 + l16]) * inv[r];
      }
  }
}

extern "C" void kernel_launch(void* const* d_in, const int* in_sizes, int n_in,
                              void* d_out, int out_size, void* d_ws, size_t ws_size,
                              hipStream_t stream) {
  const float* x  = (const float*)d_in[0];
  const float* Wk = (const float*)d_in[1];
  const float* Wq = (const float*)d_in[2];
  const float* Wv = (const float*)d_in[3];
  float* out = (float*)d_out;

  char* ws = (char*)d_ws;
  unsigned short* Wt  = (unsigned short*)(ws);                        // 1.5 MB
  unsigned short* kqv = (unsigned short*)(ws + 1572864);              // 12 MB
  unsigned short* vT  = (unsigned short*)(ws + 1572864 + 12582912);   // 4 MB

  static bool attr_set = false;
  if (!attr_set) {
    (void)hipFuncSetAttribute(reinterpret_cast<const void*>(qkv_gemm),
                              hipFuncAttributeMaxDynamicSharedMemorySize,
                              114688);
    attr_set = true;
  }

  hipLaunchKernelGGL(wt_kernel, dim3(64, 4, 3), dim3(256), 0, stream, Wk, Wq, Wv, Wt);
  hipLaunchKernelGGL(qkv_gemm, dim3(256), dim3(512), 114688, stream, x, Wt, kqv, vT);
  hipLaunchKernelGGL(attn_kernel, dim3(8, 64), dim3(256), 0, stream, kqv, vT, out);
}

// Round 11
// 230.418 us; speedup vs baseline: 1.4741x; 1.0070x over previous
//
#include <hip/hip_runtime.h>
#include <hip/hip_bf16.h>
#include <cstdint>
#include <cstddef>

#define B_  64
#define T_  256
#define C_  2048
#define HS_ 128
#define N_  384

typedef __bf16 bf16x8 __attribute__((ext_vector_type(8)));
typedef float  floatx4 __attribute__((ext_vector_type(4)));

__device__ __forceinline__ unsigned short f2bf_rne(float f) {
  union { float f; unsigned int u; } v; v.f = f;
  unsigned int r = v.u + 0x7fffu + ((v.u >> 16) & 1u);
  return (unsigned short)(r >> 16);
}
__device__ __forceinline__ unsigned short f2bf(float f) {
  union { float f; unsigned int u; } v; v.f = f;
  return (unsigned short)((v.u + 0x8000u) >> 16);
}

__device__ __forceinline__ void async_copy16(const void* g, void* l) {
  __builtin_amdgcn_global_load_lds(
      (const __attribute__((address_space(1))) unsigned int*)g,
      (__attribute__((address_space(3))) unsigned int*)l, 16, 0, 0);
}

// ---------------- Weight transpose + bf16 cast: Wt[w*128+h][c] = W_w[c][h] ---
__global__ __launch_bounds__(256) void wt_kernel(
    const float* __restrict__ Wk, const float* __restrict__ Wq,
    const float* __restrict__ Wv, unsigned short* __restrict__ Wt) {
  __shared__ float tile[32][33];
  const int w  = blockIdx.z;
  const int c0 = blockIdx.x * 32;
  const int h0 = blockIdx.y * 32;
  const float* W = (w == 0) ? Wk : (w == 1) ? Wq : Wv;
  const int tx = threadIdx.x & 31, ty = threadIdx.x >> 5;
#pragma unroll
  for (int i = 0; i < 32; i += 8)
    tile[ty + i][tx] = W[(size_t)(c0 + ty + i) * HS_ + h0 + tx];
  __syncthreads();
#pragma unroll
  for (int i = 0; i < 32; i += 8) {
    int hh = ty + i, cc = tx;
    Wt[(size_t)(w * HS_ + h0 + hh) * C_ + c0 + cc] = f2bf_rne(tile[cc][hh]);
  }
}

// ---------------- QKV GEMM: BM=64 x BN=384, BK=64, 2-deep / ring-3 B --------
// R10 (232 us total, qkv ~69 us) with ONLY the loop control changed.
// R10's residual fixed cost F~3000 cy/iter = full vmcnt(0) drain at each
// STORE_A (its av regs were the NEWEST outstanding loads). Fix: issue
// B(k+2)+av(k+2) at iter k (2-deep). STORE_A(k)'s register wait becomes
// vmcnt(8) -- 8 newer loads (B(k+1),av(k+1)) stay in flight; every load
// gets TWO iterations of latency cover; vmcnt never reaches 0 in the loop.
// B ring-3 (3 x 48 KB) + As dbuf (16 KB) = 163840 B = the full 160 KiB LDS
// (precedent: HK/AITER 160KB-LDS gfx950 kernels). A regs 2-deep in two
// NAMED sets (unroll-2; rule-#20 safe; 16 VGPR).
// Hazard audit: As[k&1] write at k ordered after last readers (compute k-2)
// by barrier k-1. B(k+2) -> slot((k+2)%3) = slot(k-1): last reader
// compute(k-1) precedes barrier(k) for all waves. Tail (k2=15): no issue;
// pending drains to 0 naturally; B(30)/B(31) covered by av-register waits
// (B(t) issued before av(t) in the same guard block).
__global__ __launch_bounds__(512) void qkv_gemm(
    const float* __restrict__ X, const unsigned short* __restrict__ Wt,
    unsigned short* __restrict__ kqv, unsigned short* __restrict__ vT) {
  extern __shared__ char smem[];  // [0,147456): B ring-3; [147456,163840): As dbuf

  const int tid  = threadIdx.x;
  const int wave = tid >> 6, lane = tid & 63;
  const int quad = lane >> 4, l16 = lane & 15;

  const int m0 = blockIdx.x * 64;      // 256 blocks x 64 rows = M
  const int wm = (wave >> 2) * 32;     // {0,32}
  const int wn = (wave & 3) * 96;      // {0,96,192,288}

  // B DMA map: 384 rows x 8 chunks(16B) = 3072 slots = 6/thread.
  // Source chunk xor-swizzled (R0/R9/R10-proven pair with the read below).
  const unsigned short* bsrc[6]; int bdst[6];
#pragma unroll
  for (int r = 0; r < 6; ++r) {
    int s = r * 512 + tid;
    int n = s >> 3, sl = s & 7;
    bsrc[r] = Wt + (size_t)n * C_ + (sl ^ (n & 7)) * 8;
    bdst[r] = (r * 512 + wave * 64) * 16;   // byte offset; +lane*16 by HW
  }
  // A map: 64 rows x 16 float4-chunks = 1024 slots = 2/thread (coalesced).
  int arow[2], achk[2], awoff[2];
#pragma unroll
  for (int r = 0; r < 2; ++r) {
    int s = r * 512 + tid;
    arow[r] = s >> 4; achk[r] = s & 15;
    awoff[r] = arow[r] * 64 + (((achk[r] >> 1) ^ (arow[r] & 7)) << 3) + ((achk[r] & 1) << 2);
  }

// KT is a TILE INDEX (64 shorts per K-step along a B row).
#define ISSUE_B(KT, OFF)                                                       \
  {                                                                            \
    _Pragma("unroll")                                                          \
    for (int r = 0; r < 6; ++r)                                                \
      async_copy16(bsrc[r] + (size_t)(KT) * 64, smem + (OFF) + bdst[r]);       \
  }
// KT is a TILE INDEX (64 floats per K-step along an X row).
#define LOAD_A(AV, KT)                                                         \
  {                                                                            \
    _Pragma("unroll")                                                          \
    for (int r = 0; r < 2; ++r)                                                \
      AV[r] = *(const float4*)(X + (size_t)(m0 + arow[r]) * C_ + (KT) * 64 + achk[r] * 4); \
  }
#define STORE_A(AV, CUR)                                                       \
  {                                                                            \
    unsigned short* As_ = (unsigned short*)(smem + 147456 + (CUR) * 8192);     \
    _Pragma("unroll")                                                          \
    for (int r = 0; r < 2; ++r) {                                              \
      ushort4 b4;                                                              \
      b4.x = f2bf(AV[r].x); b4.y = f2bf(AV[r].y);                              \
      b4.z = f2bf(AV[r].z); b4.w = f2bf(AV[r].w);                              \
      *(ushort4*)&As_[awoff[r]] = b4;                                          \
    }                                                                          \
  }

  floatx4 acc[2][6] = {};

#define COMPUTE(CUR, OFF)                                                      \
  {                                                                            \
    const unsigned short* As_ = (const unsigned short*)(smem + 147456 + (CUR) * 8192); \
    const unsigned short* Bs_ = (const unsigned short*)(smem + (OFF));         \
    _Pragma("unroll")                                                          \
    for (int ks = 0; ks < 2; ++ks) {                                           \
      bf16x8 af[2], bfv[6];                                                    \
      _Pragma("unroll")                                                        \
      for (int mt = 0; mt < 2; ++mt) {                                         \
        int rr = wm + mt * 16 + l16;                                           \
        af[mt] = *(const bf16x8*)&As_[rr * 64 + (((ks * 4 + quad) ^ (rr & 7)) << 3)]; \
      }                                                                        \
      _Pragma("unroll")                                                        \
      for (int nt = 0; nt < 6; ++nt) {                                         \
        int n = wn + nt * 16 + l16;                                            \
        bfv[nt] = *(const bf16x8*)&Bs_[n * 64 + (((ks * 4 + quad) ^ (n & 7)) << 3)]; \
      }                                                                        \
      _Pragma("unroll")                                                        \
      for (int mt = 0; mt < 2; ++mt)                                           \
        _Pragma("unroll")                                                      \
        for (int nt = 0; nt < 6; ++nt)                                         \
          acc[mt][nt] = __builtin_amdgcn_mfma_f32_16x16x32_bf16(               \
              af[mt], bfv[nt], acc[mt][nt], 0, 0, 0);                          \
    }                                                                          \
  }
#define WAIT_BAR()                                                             \
  asm volatile("s_waitcnt lgkmcnt(0)\n\ts_waitcnt vmcnt(8)" ::: "memory");     \
  __builtin_amdgcn_s_barrier()

  // ---- prologue: 2 tiles in flight. Order per tile: B first, then av
  // (so draining av(t) implies B(t) landed).
  float4 a0[2], a1[2];
  int off0 = 0, off1 = 49152, off2 = 98304;  // B(k), B(k+1), issue target
  ISSUE_B(0, off0);
  LOAD_A(a0, 0);
  ISSUE_B(1, off1);
  LOAD_A(a1, 1);

  for (int k2 = 0; k2 < 16; ++k2) {
    // ---- even step k = 2*k2 (uses a0, As[0])
    STORE_A(a0, 0);                    // compiler waits av(k): vmcnt(8)
    WAIT_BAR();                        // B(k)+As[0] visible; 8 loads in flight
    if (k2 < 15) { ISSUE_B(2 * k2 + 2, off2); LOAD_A(a0, 2 * k2 + 2); }
    COMPUTE(0, off0);
    { int t = off0; off0 = off1; off1 = off2; off2 = t; }
    // ---- odd step k = 2*k2+1 (uses a1, As[1])
    STORE_A(a1, 1);
    WAIT_BAR();
    if (k2 < 15) { ISSUE_B(2 * k2 + 3, off2); LOAD_A(a1, 2 * k2 + 3); }
    COMPUTE(1, off0);
    { int t = off0; off0 = off1; off1 = off2; off2 = t; }
  }
  asm volatile("s_waitcnt vmcnt(0)" ::: "memory");  // safety drain
#undef ISSUE_B
#undef LOAD_A
#undef STORE_A
#undef COMPUTE
#undef WAIT_BAR

  // ---- epilogue: C/D layout col=lane&15, row=quad*4+reg
#pragma unroll
  for (int mt = 0; mt < 2; ++mt)
#pragma unroll
    for (int nt = 0; nt < 6; ++nt)
#pragma unroll
      for (int r = 0; r < 4; ++r) {
        int row = m0 + wm + mt * 16 + quad * 4 + r;
        int col = wn + nt * 16 + l16;
        unsigned short us = f2bf(acc[mt][nt][r]);
        kqv[(size_t)row * N_ + col] = us;
        if (col >= 256) {   // V region -> also store transposed
          int bb = row >> 8, tt = row & 255;
          vT[(size_t)bb * HS_ * T_ + (size_t)(col - 256) * T_ + tt] = us;
        }
      }
}

// ---------------- Attention: 4 waves/block, 2 waves per 16-row t-tile -------
// Wave (tile, par): handles s-tiles st with st&1==par, packed densely in its
// private P buffer. Partial O (unnormalized) + partial rowsum combined in LDS.
// Tile pairing {x, 15-x}: equal causal work per block. (Best-config attn.)
__global__ __launch_bounds__(256) void attn_kernel(
    const unsigned short* __restrict__ kqv, const unsigned short* __restrict__ vT,
    float* __restrict__ out) {
  __shared__ unsigned short P[4][16 * 136];  // 17.4 KB, per-wave packed P
  __shared__ float Olds[2][16][132];         // 16.9 KB (pad 132)
  __shared__ float rs1[2][16];

  const int tid  = threadIdx.x;
  const int wave = tid >> 6, lane = tid & 63;
  const int quad = lane >> 4, l16 = lane & 15;
  const int tile = wave >> 1, par = wave & 1;
  const int tt = tile ? (15 - (int)blockIdx.x) : (int)blockIdx.x;  // balanced pair
  const int b  = blockIdx.y;
  const int t0 = tt * 16;
  const float scale = 0.022097086912079612f; // 2048^-0.5
  const unsigned short* kq = kqv + (size_t)b * T_ * N_;

  // k fragments (A operand), rows t0..t0+15
  bf16x8 kf[4];
#pragma unroll
  for (int ks = 0; ks < 4; ++ks)
    kf[ks] = *(const bf16x8*)&kq[(size_t)(t0 + l16) * N_ + ks * 32 + quad * 8];

  const int n_my = ((tt + 1) + (1 - par)) >> 1;  // my s-tile count
  const int npad = (n_my + 1) & ~1;              // padded to even

  float rsum[4] = {0.f, 0.f, 0.f, 0.f};

  // ---- S = k q^T over my s-tiles, exp+mask, pack into P (manual prefetch)
  bf16x8 qf[4];
  if (n_my > 0) {
    const int st = par;
#pragma unroll
    for (int ks = 0; ks < 4; ++ks)
      qf[ks] = *(const bf16x8*)&kq[(size_t)(st * 16 + l16) * N_ + HS_ + ks * 32 + quad * 8];
  }
  for (int j = 0; j < n_my; ++j) {
    bf16x8 qn[4];
    if (j + 1 < n_my) {
      const int st = par + 2 * (j + 1);
#pragma unroll
      for (int ks = 0; ks < 4; ++ks)
        qn[ks] = *(const bf16x8*)&kq[(size_t)(st * 16 + l16) * N_ + HS_ + ks * 32 + quad * 8];
    }
    floatx4 a = {};
#pragma unroll
    for (int ks = 0; ks < 4; ++ks)
      a = __builtin_amdgcn_mfma_f32_16x16x32_bf16(kf[ks], qf[ks], a, 0, 0, 0);
    const int st = par + 2 * j;
    const int scol = st * 16 + l16;
#pragma unroll
    for (int r = 0; r < 4; ++r) {
      int trow = t0 + quad * 4 + r;
      float p = (scol <= trow) ? __expf(a[r] * scale) : 0.f;
      rsum[r] += p;
      P[wave][(quad * 4 + r) * 136 + j * 16 + l16] = f2bf(p);
    }
#pragma unroll
    for (int ks = 0; ks < 4; ++ks) qf[ks] = qn[ks];
  }
  if (npad > n_my) {  // zero-fill the odd tail tile
#pragma unroll
    for (int r = 0; r < 4; ++r)
      P[wave][(quad * 4 + r) * 136 + n_my * 16 + l16] = 0;
  }
  // row sums: reduce across the 16 lanes of each quad
#pragma unroll
  for (int m = 1; m < 16; m <<= 1)
#pragma unroll
    for (int r = 0; r < 4; ++r)
      rsum[r] += __shfl_xor(rsum[r], m, 64);

  // ---- O_partial = P @ V over packed k-steps (manual prefetch)
  floatx4 oacc[8] = {};
  const unsigned short* vb = vT + (size_t)b * HS_ * T_;
  const int nks = npad >> 1;
  const int sb_off = (quad >> 1);        // which packed 16-tile inside 32-k
  const int sb_lo  = (quad & 1) * 8;
  bf16x8 bv[8]; bf16x8 pa;
  if (nks > 0) {
    int st = par + 2 * (0 + sb_off);
    int sbase = st * 16 + sb_lo;
    pa = *(const bf16x8*)&P[wave][l16 * 136 + 0 * 32 + quad * 8];
#pragma unroll
    for (int nt = 0; nt < 8; ++nt)
      bv[nt] = *(const bf16x8*)&vb[(size_t)(nt * 16 + l16) * T_ + sbase];
  }
  for (int ks2 = 0; ks2 < nks; ++ks2) {
    bf16x8 bvn[8]; bf16x8 pan;
    if (ks2 + 1 < nks) {
      int jt = 2 * (ks2 + 1) + sb_off;
      int st = par + 2 * jt;
      int sbase = st * 16 + sb_lo;
      pan = *(const bf16x8*)&P[wave][l16 * 136 + (ks2 + 1) * 32 + quad * 8];
#pragma unroll
      for (int nt = 0; nt < 8; ++nt)
        bvn[nt] = *(const bf16x8*)&vb[(size_t)(nt * 16 + l16) * T_ + sbase];
    }
#pragma unroll
    for (int nt = 0; nt < 8; ++nt)
      oacc[nt] = __builtin_amdgcn_mfma_f32_16x16x32_bf16(pa, bv[nt], oacc[nt], 0, 0, 0);
    pa = pan;
#pragma unroll
    for (int nt = 0; nt < 8; ++nt) bv[nt] = bvn[nt];
  }

  // ---- combine partials across the two parity waves of each tile
  if (par == 1) {
#pragma unroll
    for (int nt = 0; nt < 8; ++nt)
#pragma unroll
      for (int r = 0; r < 4; ++r)
        Olds[tile][quad * 4 + r][nt * 16 + l16] = oacc[nt][r];
    if (l16 == 0) {
#pragma unroll
      for (int r = 0; r < 4; ++r) rs1[tile][quad * 4 + r] = rsum[r];
    }
  }
  __syncthreads();
  if (par == 0) {
    float inv[4];
#pragma unroll
    for (int r = 0; r < 4; ++r)
      inv[r] = 1.f / (rsum[r] + rs1[tile][quad * 4 + r]);
    float* ob = out + ((size_t)b * T_ + t0) * HS_;
#pragma unroll
    for (int nt = 0; nt < 8; ++nt)
#pragma unroll
      for (int r = 0; r < 4; ++r) {
        int row = quad * 4 + r;
        ob[(size_t)row * HS_ + nt * 16 + l16] =
            (oacc[nt][r] + Olds[tile][row][nt * 16 + l16]) * inv[r];
      }
  }
}

extern "C" void kernel_launch(void* const* d_in, const int* in_sizes, int n_in,
                              void* d_out, int out_size, void* d_ws, size_t ws_size,
                              hipStream_t stream) {
  const float* x  = (const float*)d_in[0];
  const float* Wk = (const float*)d_in[1];
  const float* Wq = (const float*)d_in[2];
  const float* Wv = (const float*)d_in[3];
  float* out = (float*)d_out;

  char* ws = (char*)d_ws;
  unsigned short* Wt  = (unsigned short*)(ws);                        // 1.5 MB
  unsigned short* kqv = (unsigned short*)(ws + 1572864);              // 12 MB
  unsigned short* vT  = (unsigned short*)(ws + 1572864 + 12582912);   // 4 MB

  static bool attr_set = false;
  if (!attr_set) {
    (void)hipFuncSetAttribute(reinterpret_cast<const void*>(qkv_gemm),
                              hipFuncAttributeMaxDynamicSharedMemorySize,
                              163840);
    attr_set = true;
  }

  hipLaunchKernelGGL(wt_kernel, dim3(64, 4, 3), dim3(256), 0, stream, Wk, Wq, Wv, Wt);
  hipLaunchKernelGGL(qkv_gemm, dim3(256), dim3(512), 163840, stream, x, Wt, kqv, vT);
  hipLaunchKernelGGL(attn_kernel, dim3(8, 64), dim3(256), 0, stream, kqv, vT, out);
}